// Round 5
// baseline (288.113 us; speedup 1.0000x reference)
//
#include <hip/hip_runtime.h>
#include <hip/hip_bf16.h>
#include <math.h>

#define CB   128   // input channels
#define CMID 64    // compressed channels
#define NENC 100   // encoder out channels (25 * 2 * 2)
#define HH   48
#define WW   48
#define BB   4
#define HW   (HH*WW)          // 2304
#define H2   (HH*2)           // 96
#define W2   (WW*2)           // 96

// ---------------- Kernel 1: per-batch gamma ----------------
__global__ void gamma_kernel(const float* __restrict__ x, float* __restrict__ gamma) {
    int b = blockIdx.x;
    const float* xb = x + (size_t)b * CB * HW;
    float s = 0.f, s2 = 0.f;
    for (int i = threadIdx.x; i < HW; i += blockDim.x) {
        float g = 0.299f * xb[i] + 0.587f * xb[HW + i] + 0.114f * xb[2 * HW + i];
        s += g; s2 += g * g;
    }
    for (int o = 32; o > 0; o >>= 1) {
        s  += __shfl_down(s, o);
        s2 += __shfl_down(s2, o);
    }
    __shared__ float ss[4], ss2[4];
    int wid = threadIdx.x >> 6;
    if ((threadIdx.x & 63) == 0) { ss[wid] = s; ss2[wid] = s2; }
    __syncthreads();
    if (threadIdx.x == 0) {
        float S = 0.f, S2 = 0.f;
        int nw = blockDim.x >> 6;
        for (int i = 0; i < nw; i++) { S += ss[i]; S2 += ss2[i]; }
        const float N = (float)HW;
        float gm = S / N;
        float var = (S2 - S * S / N) / (N - 1.0f);
        var = fmaxf(var, 0.f);
        float gs = sqrtf(var);
        float gam = 0.8f + 0.4f * gm / (gm + fmaxf(gs, 1e-6f));
        gam = fminf(fmaxf(gam, 0.8f), 1.2f);
        gamma[b] = gam;
    }
}

// ---------------- Kernel 2: xg = pow(x + eps, gamma[b]), float4 ----------------
__global__ void pow_kernel(const float* __restrict__ x, const float* __restrict__ gamma,
                           float* __restrict__ xg) {
    int idx = blockIdx.x * blockDim.x + threadIdx.x;
    const int total4 = BB * CB * HW / 4;
    if (idx >= total4) return;
    int b = idx / (CB * HW / 4);
    float gam = gamma[b];
    float4 xv = ((const float4*)x)[idx];
    float4 r;
    r.x = powf(xv.x + 1e-6f, gam);
    r.y = powf(xv.y + 1e-6f, gam);
    r.z = powf(xv.z + 1e-6f, gam);
    r.w = powf(xv.w + 1e-6f, gam);
    ((float4*)xg)[idx] = r;
}

// ---------------- Kernel 3: conv1x1 + BN + SiLU, float4 over pixels ----------------
__global__ void conv1_kernel(const float* __restrict__ xg, const float* __restrict__ w,
                             const float* __restrict__ g, const float* __restrict__ bta,
                             const float* __restrict__ m, const float* __restrict__ vv,
                             float* __restrict__ y1) {
    int idx = blockIdx.x * blockDim.x + threadIdx.x;
    const int PG = HW / 4;                 // 576 pixel-groups
    const int total = BB * CMID * PG;
    if (idx >= total) return;
    int pg = idx % PG;
    int cm = (idx / PG) % CMID;
    int b  = idx / (CMID * PG);
    const float4* xb = (const float4*)(xg + (size_t)b * CB * HW) + pg;
    const float* wc = w + cm * CB;
    float4 acc = {0.f, 0.f, 0.f, 0.f};
#pragma unroll 8
    for (int c = 0; c < CB; c++) {
        float4 xv = xb[(size_t)c * PG];
        float wv = wc[c];
        acc.x = fmaf(wv, xv.x, acc.x);
        acc.y = fmaf(wv, xv.y, acc.y);
        acc.z = fmaf(wv, xv.z, acc.z);
        acc.w = fmaf(wv, xv.w, acc.w);
    }
    float sc = g[cm] * rsqrtf(vv[cm] + 1e-3f);
    float sh = bta[cm] - m[cm] * sc;
    float4 o;
    float t;
    t = acc.x * sc + sh; o.x = t / (1.f + expf(-t));
    t = acc.y * sc + sh; o.y = t / (1.f + expf(-t));
    t = acc.z * sc + sh; o.z = t / (1.f + expf(-t));
    t = acc.w * sc + sh; o.w = t / (1.f + expf(-t));
    ((float4*)y1)[idx] = o;
}

// ---------------- Kernel 4: conv3x3 + BN ----------------
// block = (b, e); 576 threads = 48 rows x 12 col-quads (4 outputs/thread).
// 9 waves/block x 400 blocks = 3600 waves -> ~14 waves/CU (~44% occupancy),
// vs 12-wide version's 4.7 waves/CU that left conv3 latency-bound.
// Weights are block-uniform -> scalar loads.
__global__ __launch_bounds__(576) void conv3_kernel(
        const float* __restrict__ y1, const float* __restrict__ w,
        const float* __restrict__ g, const float* __restrict__ bta,
        const float* __restrict__ m, const float* __restrict__ vv,
        float* __restrict__ wk2) {
    int be = blockIdx.x;
    int b = be / NENC, e = be % NENC;
    int t = threadIdx.x;
    int row = t / 12;             // 0..47
    int c0 = (t % 12) * 4;        // 0,4,...,44
    const float* wbase = w + (size_t)e * CMID * 9;
    const float* yb = y1 + (size_t)b * CMID * HW;
    float acc0 = 0.f, acc1 = 0.f, acc2 = 0.f, acc3 = 0.f;

#pragma unroll 2
    for (int cm = 0; cm < CMID; cm++) {
        const float* yc = yb + (size_t)cm * HW;
        const float* wk = wbase + cm * 9;
#pragma unroll
        for (int r = 0; r < 3; r++) {
            int hy = row + r - 1;
            if (hy < 0 || hy >= HH) continue;
            const float* yr = yc + hy * WW;
            float4 mid = *(const float4*)(yr + c0);
            float lf = (c0 > 0)      ? yr[c0 - 1] : 0.f;
            float rt = (c0 + 4 < WW) ? yr[c0 + 4] : 0.f;
            float wa = wk[r * 3 + 0], wb2 = wk[r * 3 + 1], wc2 = wk[r * 3 + 2];
            acc0 = fmaf(wa, lf,    fmaf(wb2, mid.x, fmaf(wc2, mid.y, acc0)));
            acc1 = fmaf(wa, mid.x, fmaf(wb2, mid.y, fmaf(wc2, mid.z, acc1)));
            acc2 = fmaf(wa, mid.y, fmaf(wb2, mid.z, fmaf(wc2, mid.w, acc2)));
            acc3 = fmaf(wa, mid.z, fmaf(wb2, mid.w, fmaf(wc2, rt,    acc3)));
        }
    }
    float sc = g[e] * rsqrtf(vv[e] + 1e-3f);
    float sh = bta[e] - m[e] * sc;
    float4 o = {acc0 * sc + sh, acc1 * sc + sh, acc2 * sc + sh, acc3 * sc + sh};
    *(float4*)(wk2 + (size_t)(b * NENC + e) * HW + row * WW + c0) = o;
}

// ---------------- Kernel 5: pixel-shuffled softmax -> wsm[b][25][H2][W2] ----------------
__global__ void softmax_kernel(const float* __restrict__ wk2, float* __restrict__ wsm) {
    int idx = blockIdx.x * blockDim.x + threadIdx.x;
    const int total = BB * H2 * W2;
    if (idx >= total) return;
    int Wp = idx % W2, Hp = (idx / W2) % H2, b = idx / (H2 * W2);
    int h = Hp >> 1, w = Wp >> 1;
    int off = 2 * (Hp & 1) + (Wp & 1);
    const float* base = wk2 + (size_t)b * NENC * HW + (size_t)off * HW + h * WW + w;
    float vals[25];
    float mx = -1e30f;
#pragma unroll
    for (int k = 0; k < 25; k++) {
        float tv = base[(size_t)(4 * k) * HW];
        vals[k] = tv; mx = fmaxf(mx, tv);
    }
    float sum = 0.f;
#pragma unroll
    for (int k = 0; k < 25; k++) { float e2 = expf(vals[k] - mx); vals[k] = e2; sum += e2; }
    float inv = 1.f / sum;
#pragma unroll
    for (int k = 0; k < 25; k++)
        wsm[((size_t)(b * 25 + k) * H2 + Hp) * W2 + Wp] = vals[k] * inv;
}

// ---------------- Kernel 6: CARAFE gather ----------------
// thread = (b,c,h,w): 25 shared x-loads feed all 4 sub-pixel outputs (100 FMA).
__global__ void gather_kernel(const float* __restrict__ xg, const float* __restrict__ wsm,
                              float* __restrict__ out) {
    int idx = blockIdx.x * blockDim.x + threadIdx.x;
    const int total = BB * CB * HW;
    if (idx >= total) return;
    int w = idx % WW;
    int h = (idx / WW) % HH;
    int c = (idx / HW) % CB;
    int b = idx / (CB * HW);
    const float* xb = xg + ((size_t)b * CB + c) * HW;
    float xv[25];
#pragma unroll
    for (int i = 0; i < 5; i++) {
        int hy = h + i - 2;
        bool hok = (hy >= 0) && (hy < HH);
#pragma unroll
        for (int j = 0; j < 5; j++) {
            int wx = w + j - 2;
            bool ok = hok && (wx >= 0) && (wx < WW);
            xv[i * 5 + j] = ok ? xb[hy * WW + wx] : 0.f;
        }
    }
    float a0 = 0.f, a1 = 0.f, a2 = 0.f, a3 = 0.f;
    const float* wb = wsm + (size_t)b * 25 * H2 * W2;
    int r0 = (2 * h) * W2 + 2 * w;
#pragma unroll
    for (int k = 0; k < 25; k++) {
        const float* wkp = wb + (size_t)k * H2 * W2;
        float2 w0 = *(const float2*)(wkp + r0);
        float2 w1 = *(const float2*)(wkp + r0 + W2);
        float xk = xv[k];
        a0 = fmaf(w0.x, xk, a0);
        a1 = fmaf(w0.y, xk, a1);
        a2 = fmaf(w1.x, xk, a2);
        a3 = fmaf(w1.y, xk, a3);
    }
    float* ob = out + (((size_t)b * CB + c) * H2 + 2 * h) * W2 + 2 * w;
    float2 s0 = {a0, a1};
    float2 s1 = {a2, a3};
    *(float2*)ob = s0;
    *(float2*)(ob + W2) = s1;
}

extern "C" void kernel_launch(void* const* d_in, const int* in_sizes, int n_in,
                              void* d_out, int out_size, void* d_ws, size_t ws_size,
                              hipStream_t stream) {
    const float* x       = (const float*)d_in[0];
    const float* comp_w  = (const float*)d_in[1];
    const float* comp_g  = (const float*)d_in[2];
    const float* comp_b  = (const float*)d_in[3];
    const float* comp_m  = (const float*)d_in[4];
    const float* comp_v  = (const float*)d_in[5];
    const float* enc_w   = (const float*)d_in[6];
    const float* enc_g   = (const float*)d_in[7];
    const float* enc_b   = (const float*)d_in[8];
    const float* enc_m   = (const float*)d_in[9];
    const float* enc_v   = (const float*)d_in[10];
    float* out = (float*)d_out;

    float* ws = (float*)d_ws;
    float* gamma = ws;                                   // 64 (padded)
    float* xg    = ws + 64;                              // 1,179,648
    float* wk2   = xg + (size_t)BB * CB * HW;            // 921,600
    float* y1    = wk2 + (size_t)BB * NENC * HW;         // 589,824 (dead after conv3)
    float* wsm   = y1;                                   // 921,600 (overlays y1; needs its own tail)
    // total floats: 64 + 1179648 + 921600 + 921600 = 3,022,912 (~12.1 MB)

    gamma_kernel<<<BB, 256, 0, stream>>>(x, gamma);

    {
        int total4 = BB * CB * HW / 4;
        pow_kernel<<<(total4 + 255) / 256, 256, 0, stream>>>(x, gamma, xg);
    }
    {
        int total = BB * CMID * (HW / 4);
        conv1_kernel<<<(total + 255) / 256, 256, 0, stream>>>(
            xg, comp_w, comp_g, comp_b, comp_m, comp_v, y1);
    }
    conv3_kernel<<<BB * NENC, 576, 0, stream>>>(
        y1, enc_w, enc_g, enc_b, enc_m, enc_v, wk2);
    {
        int total = BB * H2 * W2;
        softmax_kernel<<<(total + 255) / 256, 256, 0, stream>>>(wk2, wsm);
    }
    {
        int total = BB * CB * HW;
        gather_kernel<<<(total + 255) / 256, 256, 0, stream>>>(xg, wsm, out);
    }
}

// Round 7
// 231.524 us; speedup vs baseline: 1.2444x; 1.2444x over previous
//
#include <hip/hip_runtime.h>
#include <hip/hip_bf16.h>
#include <math.h>

#define CB   128   // input channels
#define CMID 64    // compressed channels
#define NENC 100   // encoder out channels (25 * 2 * 2)
#define HH   48
#define WW   48
#define BB   4
#define HW   (HH*WW)          // 2304
#define H2   (HH*2)           // 96
#define W2   (WW*2)           // 96
#define PS   56                // padded row stride: 56*4B = 224B = 14*16B -> rows 16B-aligned
#define PROWS 50               // 48 interior rows + 1 halo row each side
#define PCOL0 4                // interior starts at col 4 (cols 0..3 and 52..55 are halo/pad)
#define PLANE (PROWS*PS)       // 2800 floats per (b,cm) plane
#define Y1P_FLOATS (BB*CMID*PLANE)  // 716,800

// ---------------- Kernel 0: zero padded y1 buffer (ws is poisoned each launch) ----
__global__ void zero_kernel(float4* __restrict__ p, int n4) {
    int idx = blockIdx.x * blockDim.x + threadIdx.x;
    if (idx < n4) p[idx] = make_float4(0.f, 0.f, 0.f, 0.f);
}

// ---------------- Kernel 1: per-batch gamma ----------------
__global__ void gamma_kernel(const float* __restrict__ x, float* __restrict__ gamma) {
    int b = blockIdx.x;
    const float* xb = x + (size_t)b * CB * HW;
    float s = 0.f, s2 = 0.f;
    for (int i = threadIdx.x; i < HW; i += blockDim.x) {
        float g = 0.299f * xb[i] + 0.587f * xb[HW + i] + 0.114f * xb[2 * HW + i];
        s += g; s2 += g * g;
    }
    for (int o = 32; o > 0; o >>= 1) {
        s  += __shfl_down(s, o);
        s2 += __shfl_down(s2, o);
    }
    __shared__ float ss[4], ss2[4];
    int wid = threadIdx.x >> 6;
    if ((threadIdx.x & 63) == 0) { ss[wid] = s; ss2[wid] = s2; }
    __syncthreads();
    if (threadIdx.x == 0) {
        float S = 0.f, S2 = 0.f;
        int nw = blockDim.x >> 6;
        for (int i = 0; i < nw; i++) { S += ss[i]; S2 += ss2[i]; }
        const float N = (float)HW;
        float gm = S / N;
        float var = (S2 - S * S / N) / (N - 1.0f);
        var = fmaxf(var, 0.f);
        float gs = sqrtf(var);
        float gam = 0.8f + 0.4f * gm / (gm + fmaxf(gs, 1e-6f));
        gam = fminf(fmaxf(gam, 0.8f), 1.2f);
        gamma[b] = gam;
    }
}

// ---------------- Kernel 2: xg = pow(x + eps, gamma[b]), float4 ----------------
__global__ void pow_kernel(const float* __restrict__ x, const float* __restrict__ gamma,
                           float* __restrict__ xg) {
    int idx = blockIdx.x * blockDim.x + threadIdx.x;
    const int total4 = BB * CB * HW / 4;
    if (idx >= total4) return;
    int b = idx / (CB * HW / 4);
    float gam = gamma[b];
    float4 xv = ((const float4*)x)[idx];
    float4 r;
    r.x = powf(xv.x + 1e-6f, gam);
    r.y = powf(xv.y + 1e-6f, gam);
    r.z = powf(xv.z + 1e-6f, gam);
    r.w = powf(xv.w + 1e-6f, gam);
    ((float4*)xg)[idx] = r;
}

// ---------------- Kernel 3: conv1x1 + BN + SiLU -> PADDED y1p (aligned stores) ----
__global__ void conv1_kernel(const float* __restrict__ xg, const float* __restrict__ w,
                             const float* __restrict__ g, const float* __restrict__ bta,
                             const float* __restrict__ m, const float* __restrict__ vv,
                             float* __restrict__ y1p) {
    int idx = blockIdx.x * blockDim.x + threadIdx.x;
    const int PG = HW / 4;                 // 576 pixel-groups
    const int total = BB * CMID * PG;
    if (idx >= total) return;
    int pg = idx % PG;
    int cm = (idx / PG) % CMID;
    int b  = idx / (CMID * PG);
    const float4* xb = (const float4*)(xg + (size_t)b * CB * HW) + pg;
    const float* wc = w + cm * CB;
    float4 acc = {0.f, 0.f, 0.f, 0.f};
#pragma unroll 8
    for (int c = 0; c < CB; c++) {
        float4 xv = xb[(size_t)c * PG];
        float wv = wc[c];
        acc.x = fmaf(wv, xv.x, acc.x);
        acc.y = fmaf(wv, xv.y, acc.y);
        acc.z = fmaf(wv, xv.z, acc.z);
        acc.w = fmaf(wv, xv.w, acc.w);
    }
    float sc = g[cm] * rsqrtf(vv[cm] + 1e-3f);
    float sh = bta[cm] - m[cm] * sc;
    float4 o;
    float t;
    t = acc.x * sc + sh; o.x = t / (1.f + expf(-t));
    t = acc.y * sc + sh; o.y = t / (1.f + expf(-t));
    t = acc.z * sc + sh; o.z = t / (1.f + expf(-t));
    t = acc.w * sc + sh; o.w = t / (1.f + expf(-t));
    int row = pg / 12, col = (pg % 12) * 4;
    // interior at (row+1, col+PCOL0): offset = (row+1)*56 + col+4 == 0 (mod 4) -> 16B-aligned
    float* dst = y1p + ((size_t)(b * CMID + cm)) * PLANE + (row + 1) * PS + (col + PCOL0);
    *(float4*)dst = o;
}

// ---------------- Kernel 4: conv3x3 + BN (branch-free, zero-halo, aligned loads) ----
// block = (b, e); 576 threads = 48 rows x 12 col-quads (4 outputs/thread).
// All loads unconditional; mid is 16B-aligned float4; cm-loop unrolls & pipelines.
__global__ __launch_bounds__(576) void conv3_kernel(
        const float* __restrict__ y1p, const float* __restrict__ w,
        const float* __restrict__ g, const float* __restrict__ bta,
        const float* __restrict__ m, const float* __restrict__ vv,
        float* __restrict__ wk2) {
    int be = blockIdx.x;
    int b = be / NENC, e = be % NENC;
    int t = threadIdx.x;
    int row = t / 12;             // 0..47
    int c0 = (t % 12) * 4;        // 0,4,...,44
    const float* wbase = w + (size_t)e * CMID * 9;
    // padded rows row..row+2 cover input rows row-1..row+1; col c0+PCOL0 = input col c0
    const float* yb = y1p + (size_t)b * CMID * PLANE + row * PS + (c0 + PCOL0);
    float acc0 = 0.f, acc1 = 0.f, acc2 = 0.f, acc3 = 0.f;

#pragma unroll 4
    for (int cm = 0; cm < CMID; cm++) {
        const float* yc = yb + (size_t)cm * PLANE;
        const float* wk = wbase + cm * 9;
#pragma unroll
        for (int r = 0; r < 3; r++) {
            const float* yr = yc + r * PS;
            float  lf  = yr[-1];                  // input col c0-1 (halo zero at c0=0)
            float4 mid = *(const float4*)(yr);    // input cols c0..c0+3, 16B-aligned
            float  rt  = yr[4];                   // input col c0+4 (halo zero at c0=44)
            float wa = wk[r * 3 + 0], wb2 = wk[r * 3 + 1], wc2 = wk[r * 3 + 2];
            acc0 = fmaf(wa, lf,    fmaf(wb2, mid.x, fmaf(wc2, mid.y, acc0)));
            acc1 = fmaf(wa, mid.x, fmaf(wb2, mid.y, fmaf(wc2, mid.z, acc1)));
            acc2 = fmaf(wa, mid.y, fmaf(wb2, mid.z, fmaf(wc2, mid.w, acc2)));
            acc3 = fmaf(wa, mid.z, fmaf(wb2, mid.w, fmaf(wc2, rt,    acc3)));
        }
    }
    float sc = g[e] * rsqrtf(vv[e] + 1e-3f);
    float sh = bta[e] - m[e] * sc;
    float4 o = {acc0 * sc + sh, acc1 * sc + sh, acc2 * sc + sh, acc3 * sc + sh};
    *(float4*)(wk2 + (size_t)(b * NENC + e) * HW + row * WW + c0) = o;
}

// ---------------- Kernel 5: pixel-shuffled softmax -> wsm[b][25][H2][W2] ----------------
__global__ void softmax_kernel(const float* __restrict__ wk2, float* __restrict__ wsm) {
    int idx = blockIdx.x * blockDim.x + threadIdx.x;
    const int total = BB * H2 * W2;
    if (idx >= total) return;
    int Wp = idx % W2, Hp = (idx / W2) % H2, b = idx / (H2 * W2);
    int h = Hp >> 1, w = Wp >> 1;
    int off = 2 * (Hp & 1) + (Wp & 1);
    const float* base = wk2 + (size_t)b * NENC * HW + (size_t)off * HW + h * WW + w;
    float vals[25];
    float mx = -1e30f;
#pragma unroll
    for (int k = 0; k < 25; k++) {
        float tv = base[(size_t)(4 * k) * HW];
        vals[k] = tv; mx = fmaxf(mx, tv);
    }
    float sum = 0.f;
#pragma unroll
    for (int k = 0; k < 25; k++) { float e2 = expf(vals[k] - mx); vals[k] = e2; sum += e2; }
    float inv = 1.f / sum;
#pragma unroll
    for (int k = 0; k < 25; k++)
        wsm[((size_t)(b * 25 + k) * H2 + Hp) * W2 + Wp] = vals[k] * inv;
}

// ---------------- Kernel 6: CARAFE gather ----------------
// thread = (b,c,h,w): 25 shared x-loads feed all 4 sub-pixel outputs (100 FMA).
__global__ void gather_kernel(const float* __restrict__ xg, const float* __restrict__ wsm,
                              float* __restrict__ out) {
    int idx = blockIdx.x * blockDim.x + threadIdx.x;
    const int total = BB * CB * HW;
    if (idx >= total) return;
    int w = idx % WW;
    int h = (idx / WW) % HH;
    int c = (idx / HW) % CB;
    int b = idx / (CB * HW);
    const float* xb = xg + ((size_t)b * CB + c) * HW;
    float xv[25];
#pragma unroll
    for (int i = 0; i < 5; i++) {
        int hy = h + i - 2;
        bool hok = (hy >= 0) && (hy < HH);
#pragma unroll
        for (int j = 0; j < 5; j++) {
            int wx = w + j - 2;
            bool ok = hok && (wx >= 0) && (wx < WW);
            xv[i * 5 + j] = ok ? xb[hy * WW + wx] : 0.f;
        }
    }
    float a0 = 0.f, a1 = 0.f, a2 = 0.f, a3 = 0.f;
    const float* wb = wsm + (size_t)b * 25 * H2 * W2;
    int r0 = (2 * h) * W2 + 2 * w;
#pragma unroll
    for (int k = 0; k < 25; k++) {
        const float* wkp = wb + (size_t)k * H2 * W2;
        float2 w0 = *(const float2*)(wkp + r0);
        float2 w1 = *(const float2*)(wkp + r0 + W2);
        float xk = xv[k];
        a0 = fmaf(w0.x, xk, a0);
        a1 = fmaf(w0.y, xk, a1);
        a2 = fmaf(w1.x, xk, a2);
        a3 = fmaf(w1.y, xk, a3);
    }
    float* ob = out + (((size_t)b * CB + c) * H2 + 2 * h) * W2 + 2 * w;
    float2 s0 = {a0, a1};
    float2 s1 = {a2, a3};
    *(float2*)ob = s0;
    *(float2*)(ob + W2) = s1;
}

extern "C" void kernel_launch(void* const* d_in, const int* in_sizes, int n_in,
                              void* d_out, int out_size, void* d_ws, size_t ws_size,
                              hipStream_t stream) {
    const float* x       = (const float*)d_in[0];
    const float* comp_w  = (const float*)d_in[1];
    const float* comp_g  = (const float*)d_in[2];
    const float* comp_b  = (const float*)d_in[3];
    const float* comp_m  = (const float*)d_in[4];
    const float* comp_v  = (const float*)d_in[5];
    const float* enc_w   = (const float*)d_in[6];
    const float* enc_g   = (const float*)d_in[7];
    const float* enc_b   = (const float*)d_in[8];
    const float* enc_m   = (const float*)d_in[9];
    const float* enc_v   = (const float*)d_in[10];
    float* out = (float*)d_out;

    float* ws = (float*)d_ws;
    float* gamma = ws;                                   // 64 (padded)
    float* xg    = ws + 64;                              // 1,179,648
    float* wk2   = xg + (size_t)BB * CB * HW;            // 921,600
    float* y1p   = wk2 + (size_t)BB * NENC * HW;         // 716,800 (dead after conv3)
    float* wsm   = y1p;                                  // 921,600 (overlays y1p region)
    // region after wk2 must fit max(716,800, 921,600) = 921,600 floats
    // total floats: 64 + 1,179,648 + 921,600 + 921,600 = 3,022,912 (~12.1 MB)
    // (same footprint as the rounds that passed timing)

    {   // zero padded y1 (ws is re-poisoned 0xAA before every launch)
        int n4 = Y1P_FLOATS / 4;
        zero_kernel<<<(n4 + 255) / 256, 256, 0, stream>>>((float4*)y1p, n4);
    }
    gamma_kernel<<<BB, 256, 0, stream>>>(x, gamma);
    {
        int total4 = BB * CB * HW / 4;
        pow_kernel<<<(total4 + 255) / 256, 256, 0, stream>>>(x, gamma, xg);
    }
    {
        int total = BB * CMID * (HW / 4);
        conv1_kernel<<<(total + 255) / 256, 256, 0, stream>>>(
            xg, comp_w, comp_g, comp_b, comp_m, comp_v, y1p);
    }
    conv3_kernel<<<BB * NENC, 576, 0, stream>>>(
        y1p, enc_w, enc_g, enc_b, enc_m, enc_v, wk2);
    {
        int total = BB * H2 * W2;
        softmax_kernel<<<(total + 255) / 256, 256, 0, stream>>>(wk2, wsm);
    }
    {
        int total = BB * CB * HW;
        gather_kernel<<<(total + 255) / 256, 256, 0, stream>>>(xg, wsm, out);
    }
}

// Round 9
// 191.459 us; speedup vs baseline: 1.5048x; 1.2093x over previous
//
#include <hip/hip_runtime.h>
#include <hip/hip_bf16.h>
#include <math.h>

#define CB   128   // input channels
#define CMID 64    // compressed channels
#define NENC 100   // encoder out channels (25 * 2 * 2)
#define HH   48
#define WW   48
#define BB   4
#define HW   (HH*WW)          // 2304
#define H2   (HH*2)           // 96
#define W2   (WW*2)           // 96
#define PS   56                // padded row stride: 224B -> rows 16B-aligned
#define PROWS 50               // 48 interior rows + 1 halo row each side
#define PCOL0 4                // interior starts at col 4
#define PLANE (PROWS*PS)       // 2800 floats per (b,cm) plane
#define Y1P_FLOATS (BB*CMID*PLANE)  // 716,800

// ---------------- Kernel 0: zero padded y1 buffer ----------------
__global__ void zero_kernel(float4* __restrict__ p, int n4) {
    int idx = blockIdx.x * blockDim.x + threadIdx.x;
    if (idx < n4) p[idx] = make_float4(0.f, 0.f, 0.f, 0.f);
}

// ---------------- Kernel 1: per-batch gamma (float4 loads) ----------------
__global__ void gamma_kernel(const float* __restrict__ x, float* __restrict__ gamma) {
    int b = blockIdx.x;
    const float* xb = x + (size_t)b * CB * HW;
    const float4* R4 = (const float4*)xb;
    const float4* G4 = (const float4*)(xb + HW);
    const float4* B4 = (const float4*)(xb + 2 * HW);
    float s = 0.f, s2 = 0.f;
    for (int i = threadIdx.x; i < HW / 4; i += blockDim.x) {
        float4 r = R4[i], g = G4[i], bl = B4[i];
        float g0 = 0.299f * r.x + 0.587f * g.x + 0.114f * bl.x;
        float g1 = 0.299f * r.y + 0.587f * g.y + 0.114f * bl.y;
        float g2 = 0.299f * r.z + 0.587f * g.z + 0.114f * bl.z;
        float g3 = 0.299f * r.w + 0.587f * g.w + 0.114f * bl.w;
        s  += (g0 + g1) + (g2 + g3);
        s2 += (g0 * g0 + g1 * g1) + (g2 * g2 + g3 * g3);
    }
    for (int o = 32; o > 0; o >>= 1) {
        s  += __shfl_down(s, o);
        s2 += __shfl_down(s2, o);
    }
    __shared__ float ss[4], ss2[4];
    int wid = threadIdx.x >> 6;
    if ((threadIdx.x & 63) == 0) { ss[wid] = s; ss2[wid] = s2; }
    __syncthreads();
    if (threadIdx.x == 0) {
        float S = 0.f, S2 = 0.f;
        int nw = blockDim.x >> 6;
        for (int i = 0; i < nw; i++) { S += ss[i]; S2 += ss2[i]; }
        const float N = (float)HW;
        float gm = S / N;
        float var = (S2 - S * S / N) / (N - 1.0f);
        var = fmaxf(var, 0.f);
        float gs = sqrtf(var);
        float gam = 0.8f + 0.4f * gm / (gm + fmaxf(gs, 1e-6f));
        gam = fminf(fmaxf(gam, 0.8f), 1.2f);
        gamma[b] = gam;
    }
}

// ---------------- Kernel 2: xg = pow(x + eps, gamma[b]), float4 ----------------
__global__ void pow_kernel(const float* __restrict__ x, const float* __restrict__ gamma,
                           float* __restrict__ xg) {
    int idx = blockIdx.x * blockDim.x + threadIdx.x;
    const int total4 = BB * CB * HW / 4;
    if (idx >= total4) return;
    int b = idx / (CB * HW / 4);
    float gam = gamma[b];
    float4 xv = ((const float4*)x)[idx];
    float4 r;
    r.x = powf(xv.x + 1e-6f, gam);
    r.y = powf(xv.y + 1e-6f, gam);
    r.z = powf(xv.z + 1e-6f, gam);
    r.w = powf(xv.w + 1e-6f, gam);
    ((float4*)xg)[idx] = r;
}

// ---------------- Kernel 3: conv1x1 + BN + SiLU -> PADDED y1p ----------------
__global__ void conv1_kernel(const float* __restrict__ xg, const float* __restrict__ w,
                             const float* __restrict__ g, const float* __restrict__ bta,
                             const float* __restrict__ m, const float* __restrict__ vv,
                             float* __restrict__ y1p) {
    int idx = blockIdx.x * blockDim.x + threadIdx.x;
    const int PG = HW / 4;                 // 576 pixel-groups
    const int total = BB * CMID * PG;
    if (idx >= total) return;
    int pg = idx % PG;
    int cm = (idx / PG) % CMID;
    int b  = idx / (CMID * PG);
    const float4* xb = (const float4*)(xg + (size_t)b * CB * HW) + pg;
    const float* wc = w + cm * CB;
    float4 acc = {0.f, 0.f, 0.f, 0.f};
#pragma unroll 8
    for (int c = 0; c < CB; c++) {
        float4 xv = xb[(size_t)c * PG];
        float wv = wc[c];
        acc.x = fmaf(wv, xv.x, acc.x);
        acc.y = fmaf(wv, xv.y, acc.y);
        acc.z = fmaf(wv, xv.z, acc.z);
        acc.w = fmaf(wv, xv.w, acc.w);
    }
    float sc = g[cm] * rsqrtf(vv[cm] + 1e-3f);
    float sh = bta[cm] - m[cm] * sc;
    float4 o;
    float t;
    t = acc.x * sc + sh; o.x = t / (1.f + expf(-t));
    t = acc.y * sc + sh; o.y = t / (1.f + expf(-t));
    t = acc.z * sc + sh; o.z = t / (1.f + expf(-t));
    t = acc.w * sc + sh; o.w = t / (1.f + expf(-t));
    int row = pg / 12, col = (pg % 12) * 4;
    float* dst = y1p + ((size_t)(b * CMID + cm)) * PLANE + (row + 1) * PS + (col + PCOL0);
    *(float4*)dst = o;   // 16B-aligned
}

// ---------------- Kernel 4: conv3x3 + BN — manual dist-1 software pipeline ----
// block: 192 thr = 16 rows x 12 col-quads; grid = (b,band)x100 e (e fastest for L2).
// Named-register prefetch of cm+1's 18 floats + 9 weights during cm's 36 FMAs.
__global__ __launch_bounds__(192) void conv3_kernel(
        const float* __restrict__ y1p, const float* __restrict__ w,
        const float* __restrict__ g, const float* __restrict__ bta,
        const float* __restrict__ m, const float* __restrict__ vv,
        float* __restrict__ wk2) {
    int blk = blockIdx.x;
    int e   = blk % NENC;
    int tmp = blk / NENC;          // b*3 + band
    int rb  = tmp % 3, b = tmp / 3;
    int t   = threadIdx.x;
    int row = rb * 16 + t / 12;    // 0..47
    int c0  = (t % 12) * 4;        // 0,4,...,44
    const float* wbase = w + (size_t)e * CMID * 9;
    const float* yb = y1p + (size_t)b * CMID * PLANE + row * PS + (c0 + PCOL0);

    float acc0 = 0.f, acc1 = 0.f, acc2 = 0.f, acc3 = 0.f;

    // --- prologue: load cm=0 data + weights ---
    float  lf0 = yb[-1];          float4 m0 = *(const float4*)yb;            float rt0 = yb[4];
    float  lf1 = yb[PS - 1];      float4 m1 = *(const float4*)(yb + PS);     float rt1 = yb[PS + 4];
    float  lf2 = yb[2*PS - 1];    float4 m2 = *(const float4*)(yb + 2*PS);   float rt2 = yb[2*PS + 4];
    float w00 = wbase[0], w01 = wbase[1], w02 = wbase[2];
    float w10 = wbase[3], w11 = wbase[4], w12 = wbase[5];
    float w20 = wbase[6], w21 = wbase[7], w22 = wbase[8];

    for (int cm = 0; cm < CMID - 1; ++cm) {
        // --- issue next iteration's loads first (stay in flight under FMAs) ---
        const float* yn = yb + (size_t)(cm + 1) * PLANE;
        float  nlf0 = yn[-1];        float4 nm0 = *(const float4*)yn;          float nrt0 = yn[4];
        float  nlf1 = yn[PS - 1];    float4 nm1 = *(const float4*)(yn + PS);   float nrt1 = yn[PS + 4];
        float  nlf2 = yn[2*PS - 1];  float4 nm2 = *(const float4*)(yn + 2*PS); float nrt2 = yn[2*PS + 4];
        const float* wn = wbase + (cm + 1) * 9;
        float nw00 = wn[0], nw01 = wn[1], nw02 = wn[2];
        float nw10 = wn[3], nw11 = wn[4], nw12 = wn[5];
        float nw20 = wn[6], nw21 = wn[7], nw22 = wn[8];

        // --- compute with current registers ---
        acc0 = fmaf(w00, lf0,  fmaf(w01, m0.x, fmaf(w02, m0.y, acc0)));
        acc1 = fmaf(w00, m0.x, fmaf(w01, m0.y, fmaf(w02, m0.z, acc1)));
        acc2 = fmaf(w00, m0.y, fmaf(w01, m0.z, fmaf(w02, m0.w, acc2)));
        acc3 = fmaf(w00, m0.z, fmaf(w01, m0.w, fmaf(w02, rt0,  acc3)));
        acc0 = fmaf(w10, lf1,  fmaf(w11, m1.x, fmaf(w12, m1.y, acc0)));
        acc1 = fmaf(w10, m1.x, fmaf(w11, m1.y, fmaf(w12, m1.z, acc1)));
        acc2 = fmaf(w10, m1.y, fmaf(w11, m1.z, fmaf(w12, m1.w, acc2)));
        acc3 = fmaf(w10, m1.z, fmaf(w11, m1.w, fmaf(w12, rt1,  acc3)));
        acc0 = fmaf(w20, lf2,  fmaf(w21, m2.x, fmaf(w22, m2.y, acc0)));
        acc1 = fmaf(w20, m2.x, fmaf(w21, m2.y, fmaf(w22, m2.z, acc1)));
        acc2 = fmaf(w20, m2.y, fmaf(w21, m2.z, fmaf(w22, m2.w, acc2)));
        acc3 = fmaf(w20, m2.z, fmaf(w21, m2.w, fmaf(w22, rt2,  acc3)));

        // --- rotate ---
        lf0 = nlf0; m0 = nm0; rt0 = nrt0;
        lf1 = nlf1; m1 = nm1; rt1 = nrt1;
        lf2 = nlf2; m2 = nm2; rt2 = nrt2;
        w00 = nw00; w01 = nw01; w02 = nw02;
        w10 = nw10; w11 = nw11; w12 = nw12;
        w20 = nw20; w21 = nw21; w22 = nw22;
    }
    // --- peeled final iteration (cm = CMID-1), no prefetch ---
    acc0 = fmaf(w00, lf0,  fmaf(w01, m0.x, fmaf(w02, m0.y, acc0)));
    acc1 = fmaf(w00, m0.x, fmaf(w01, m0.y, fmaf(w02, m0.z, acc1)));
    acc2 = fmaf(w00, m0.y, fmaf(w01, m0.z, fmaf(w02, m0.w, acc2)));
    acc3 = fmaf(w00, m0.z, fmaf(w01, m0.w, fmaf(w02, rt0,  acc3)));
    acc0 = fmaf(w10, lf1,  fmaf(w11, m1.x, fmaf(w12, m1.y, acc0)));
    acc1 = fmaf(w10, m1.x, fmaf(w11, m1.y, fmaf(w12, m1.z, acc1)));
    acc2 = fmaf(w10, m1.y, fmaf(w11, m1.z, fmaf(w12, m1.w, acc2)));
    acc3 = fmaf(w10, m1.z, fmaf(w11, m1.w, fmaf(w12, rt1,  acc3)));
    acc0 = fmaf(w20, lf2,  fmaf(w21, m2.x, fmaf(w22, m2.y, acc0)));
    acc1 = fmaf(w20, m2.x, fmaf(w21, m2.y, fmaf(w22, m2.z, acc1)));
    acc2 = fmaf(w20, m2.y, fmaf(w21, m2.z, fmaf(w22, m2.w, acc2)));
    acc3 = fmaf(w20, m2.z, fmaf(w21, m2.w, fmaf(w22, rt2,  acc3)));

    float sc = g[e] * rsqrtf(vv[e] + 1e-3f);
    float sh = bta[e] - m[e] * sc;
    float4 o = {acc0 * sc + sh, acc1 * sc + sh, acc2 * sc + sh, acc3 * sc + sh};
    *(float4*)(wk2 + (size_t)(b * NENC + e) * HW + row * WW + c0) = o;
}

// ---------------- Kernel 5: pixel-shuffled softmax -> wsm[b][25][H2][W2] ----------------
__global__ void softmax_kernel(const float* __restrict__ wk2, float* __restrict__ wsm) {
    int idx = blockIdx.x * blockDim.x + threadIdx.x;
    const int total = BB * H2 * W2;
    if (idx >= total) return;
    int Wp = idx % W2, Hp = (idx / W2) % H2, b = idx / (H2 * W2);
    int h = Hp >> 1, w = Wp >> 1;
    int off = 2 * (Hp & 1) + (Wp & 1);
    const float* base = wk2 + (size_t)b * NENC * HW + (size_t)off * HW + h * WW + w;
    float vals[25];
    float mx = -1e30f;
#pragma unroll
    for (int k = 0; k < 25; k++) {
        float tv = base[(size_t)(4 * k) * HW];
        vals[k] = tv; mx = fmaxf(mx, tv);
    }
    float sum = 0.f;
#pragma unroll
    for (int k = 0; k < 25; k++) { float e2 = expf(vals[k] - mx); vals[k] = e2; sum += e2; }
    float inv = 1.f / sum;
#pragma unroll
    for (int k = 0; k < 25; k++)
        wsm[((size_t)(b * 25 + k) * H2 + Hp) * W2 + Wp] = vals[k] * inv;
}

// ---------------- Kernel 6: CARAFE gather ----------------
__global__ void gather_kernel(const float* __restrict__ xg, const float* __restrict__ wsm,
                              float* __restrict__ out) {
    int idx = blockIdx.x * blockDim.x + threadIdx.x;
    const int total = BB * CB * HW;
    if (idx >= total) return;
    int w = idx % WW;
    int h = (idx / WW) % HH;
    int c = (idx / HW) % CB;
    int b = idx / (CB * HW);
    const float* xb = xg + ((size_t)b * CB + c) * HW;
    float xv[25];
#pragma unroll
    for (int i = 0; i < 5; i++) {
        int hy = h + i - 2;
        bool hok = (hy >= 0) && (hy < HH);
#pragma unroll
        for (int j = 0; j < 5; j++) {
            int wx = w + j - 2;
            bool ok = hok && (wx >= 0) && (wx < WW);
            xv[i * 5 + j] = ok ? xb[hy * WW + wx] : 0.f;
        }
    }
    float a0 = 0.f, a1 = 0.f, a2 = 0.f, a3 = 0.f;
    const float* wb = wsm + (size_t)b * 25 * H2 * W2;
    int r0 = (2 * h) * W2 + 2 * w;
#pragma unroll
    for (int k = 0; k < 25; k++) {
        const float* wkp = wb + (size_t)k * H2 * W2;
        float2 w0 = *(const float2*)(wkp + r0);
        float2 w1 = *(const float2*)(wkp + r0 + W2);
        float xk = xv[k];
        a0 = fmaf(w0.x, xk, a0);
        a1 = fmaf(w0.y, xk, a1);
        a2 = fmaf(w1.x, xk, a2);
        a3 = fmaf(w1.y, xk, a3);
    }
    float* ob = out + (((size_t)b * CB + c) * H2 + 2 * h) * W2 + 2 * w;
    float2 s0 = {a0, a1};
    float2 s1 = {a2, a3};
    *(float2*)ob = s0;
    *(float2*)(ob + W2) = s1;
}

extern "C" void kernel_launch(void* const* d_in, const int* in_sizes, int n_in,
                              void* d_out, int out_size, void* d_ws, size_t ws_size,
                              hipStream_t stream) {
    const float* x       = (const float*)d_in[0];
    const float* comp_w  = (const float*)d_in[1];
    const float* comp_g  = (const float*)d_in[2];
    const float* comp_b  = (const float*)d_in[3];
    const float* comp_m  = (const float*)d_in[4];
    const float* comp_v  = (const float*)d_in[5];
    const float* enc_w   = (const float*)d_in[6];
    const float* enc_g   = (const float*)d_in[7];
    const float* enc_b   = (const float*)d_in[8];
    const float* enc_m   = (const float*)d_in[9];
    const float* enc_v   = (const float*)d_in[10];
    float* out = (float*)d_out;

    float* ws = (float*)d_ws;
    float* gamma = ws;                                   // 64 (padded)
    float* xg    = ws + 64;                              // 1,179,648
    float* wk2   = xg + (size_t)BB * CB * HW;            // 921,600
    float* y1p   = wk2 + (size_t)BB * NENC * HW;         // 716,800 (dead after conv3)
    float* wsm   = y1p;                                  // 921,600 (overlays y1p region)
    // region after wk2 sized max(716,800, 921,600) = 921,600 floats
    // total floats: 64 + 1,179,648 + 921,600 + 921,600 = 3,022,912 (~12.1 MB)

    {   // zero padded y1 (ws is re-poisoned 0xAA before every launch)
        int n4 = Y1P_FLOATS / 4;
        zero_kernel<<<(n4 + 255) / 256, 256, 0, stream>>>((float4*)y1p, n4);
    }
    gamma_kernel<<<BB, 256, 0, stream>>>(x, gamma);
    {
        int total4 = BB * CB * HW / 4;
        pow_kernel<<<(total4 + 255) / 256, 256, 0, stream>>>(x, gamma, xg);
    }
    {
        int total = BB * CMID * (HW / 4);
        conv1_kernel<<<(total + 255) / 256, 256, 0, stream>>>(
            xg, comp_w, comp_g, comp_b, comp_m, comp_v, y1p);
    }
    conv3_kernel<<<BB * 3 * NENC, 192, 0, stream>>>(
        y1p, enc_w, enc_g, enc_b, enc_m, enc_v, wk2);
    {
        int total = BB * H2 * W2;
        softmax_kernel<<<(total + 255) / 256, 256, 0, stream>>>(wk2, wsm);
    }
    {
        int total = BB * CB * HW;
        gather_kernel<<<(total + 255) / 256, 256, 0, stream>>>(xg, wsm, out);
    }
}

// Round 10
// 172.612 us; speedup vs baseline: 1.6691x; 1.1092x over previous
//
#include <hip/hip_runtime.h>
#include <hip/hip_bf16.h>
#include <math.h>

#define CB   128   // input channels
#define CMID 64    // compressed channels
#define NENC 100   // encoder out channels (25 * 2 * 2)
#define HH   48
#define WW   48
#define BB   4
#define HW   (HH*WW)          // 2304
#define H2   (HH*2)           // 96
#define W2   (WW*2)           // 96
#define PS   56                // padded row stride: 224B -> rows 16B-aligned
#define PROWS 50               // 48 interior rows + 1 halo row each side
#define PCOL0 4                // interior starts at col 4
#define PLANE (PROWS*PS)       // 2800 floats per (b,cm) plane
#define EG   2                 // e-outputs per conv3 block (data reuse)

// ---------------- Kernel 0: zero ONLY the halo cells conv3 reads ----------------
// Per plane: row0 (14 f4), row49 (14 f4), rows1..48 x {cols0..3, cols52..55} (96 f4)
// = 124 float4 per plane, 256 planes -> 124 blocks x 256 threads.
__global__ void halo_kernel(float* __restrict__ y1p) {
    int idx = blockIdx.x * blockDim.x + threadIdx.x;   // plane*124 + t
    int plane = idx / 124;
    int t = idx % 124;
    float* p = y1p + (size_t)plane * PLANE;
    float4 z = make_float4(0.f, 0.f, 0.f, 0.f);
    if (t < 14) {
        *(float4*)(p + t * 4) = z;                     // row 0
    } else if (t < 28) {
        *(float4*)(p + 49 * PS + (t - 14) * 4) = z;    // row 49
    } else {
        int s = t - 28;                                 // 0..95
        int r = 1 + (s >> 1);                           // 1..48
        int col = (s & 1) ? 52 : 0;
        *(float4*)(p + r * PS + col) = z;
    }
}

// ---------------- Kernel 1: per-batch gamma (float4 loads) ----------------
__global__ void gamma_kernel(const float* __restrict__ x, float* __restrict__ gamma) {
    int b = blockIdx.x;
    const float* xb = x + (size_t)b * CB * HW;
    const float4* R4 = (const float4*)xb;
    const float4* G4 = (const float4*)(xb + HW);
    const float4* B4 = (const float4*)(xb + 2 * HW);
    float s = 0.f, s2 = 0.f;
    for (int i = threadIdx.x; i < HW / 4; i += blockDim.x) {
        float4 r = R4[i], g = G4[i], bl = B4[i];
        float g0 = 0.299f * r.x + 0.587f * g.x + 0.114f * bl.x;
        float g1 = 0.299f * r.y + 0.587f * g.y + 0.114f * bl.y;
        float g2 = 0.299f * r.z + 0.587f * g.z + 0.114f * bl.z;
        float g3 = 0.299f * r.w + 0.587f * g.w + 0.114f * bl.w;
        s  += (g0 + g1) + (g2 + g3);
        s2 += (g0 * g0 + g1 * g1) + (g2 * g2 + g3 * g3);
    }
    for (int o = 32; o > 0; o >>= 1) {
        s  += __shfl_down(s, o);
        s2 += __shfl_down(s2, o);
    }
    __shared__ float ss[4], ss2[4];
    int wid = threadIdx.x >> 6;
    if ((threadIdx.x & 63) == 0) { ss[wid] = s; ss2[wid] = s2; }
    __syncthreads();
    if (threadIdx.x == 0) {
        float S = 0.f, S2 = 0.f;
        int nw = blockDim.x >> 6;
        for (int i = 0; i < nw; i++) { S += ss[i]; S2 += ss2[i]; }
        const float N = (float)HW;
        float gm = S / N;
        float var = (S2 - S * S / N) / (N - 1.0f);
        var = fmaxf(var, 0.f);
        float gs = sqrtf(var);
        float gam = 0.8f + 0.4f * gm / (gm + fmaxf(gs, 1e-6f));
        gam = fminf(fmaxf(gam, 0.8f), 1.2f);
        gamma[b] = gam;
    }
}

// ---------------- Kernel 2: xg = pow(x + eps, gamma[b]) via fast log/exp ----------
__global__ void pow_kernel(const float* __restrict__ x, const float* __restrict__ gamma,
                           float* __restrict__ xg) {
    int idx = blockIdx.x * blockDim.x + threadIdx.x;
    const int total4 = BB * CB * HW / 4;
    if (idx >= total4) return;
    int b = idx / (CB * HW / 4);
    float gam = gamma[b];
    float4 xv = ((const float4*)x)[idx];
    float4 r;
    r.x = __expf(gam * __logf(xv.x + 1e-6f));   // x+eps > 0 always
    r.y = __expf(gam * __logf(xv.y + 1e-6f));
    r.z = __expf(gam * __logf(xv.z + 1e-6f));
    r.w = __expf(gam * __logf(xv.w + 1e-6f));
    ((float4*)xg)[idx] = r;
}

// ---------------- Kernel 3: conv1x1 + BN + SiLU -> PADDED y1p ----------------
__global__ void conv1_kernel(const float* __restrict__ xg, const float* __restrict__ w,
                             const float* __restrict__ g, const float* __restrict__ bta,
                             const float* __restrict__ m, const float* __restrict__ vv,
                             float* __restrict__ y1p) {
    int idx = blockIdx.x * blockDim.x + threadIdx.x;
    const int PG = HW / 4;                 // 576 pixel-groups
    const int total = BB * CMID * PG;
    if (idx >= total) return;
    int pg = idx % PG;
    int cm = (idx / PG) % CMID;
    int b  = idx / (CMID * PG);
    const float4* xb = (const float4*)(xg + (size_t)b * CB * HW) + pg;
    const float* wc = w + cm * CB;
    float4 acc = {0.f, 0.f, 0.f, 0.f};
#pragma unroll 8
    for (int c = 0; c < CB; c++) {
        float4 xv = xb[(size_t)c * PG];
        float wv = wc[c];
        acc.x = fmaf(wv, xv.x, acc.x);
        acc.y = fmaf(wv, xv.y, acc.y);
        acc.z = fmaf(wv, xv.z, acc.z);
        acc.w = fmaf(wv, xv.w, acc.w);
    }
    float sc = g[cm] * rsqrtf(vv[cm] + 1e-3f);
    float sh = bta[cm] - m[cm] * sc;
    float4 o;
    float t;
    t = acc.x * sc + sh; o.x = t / (1.f + __expf(-t));
    t = acc.y * sc + sh; o.y = t / (1.f + __expf(-t));
    t = acc.z * sc + sh; o.z = t / (1.f + __expf(-t));
    t = acc.w * sc + sh; o.w = t / (1.f + __expf(-t));
    int row = pg / 12, col = (pg % 12) * 4;
    float* dst = y1p + ((size_t)(b * CMID + cm)) * PLANE + (row + 1) * PS + (col + PCOL0);
    *(float4*)dst = o;   // 16B-aligned
}

// ---------------- Kernel 4: conv3x3 + BN — e-blocked (EG=2) + dist-1 pipeline ----
// block: 192 thr = 16 rows x 12 col-quads; computes TWO e outputs -> the 9 loads
// per cm feed 72 FMAs (8:1). grid = (b,band) x 50 egroups, eg fastest for L2.
#define FMA4(A0,A1,A2,A3, wa,wb,wc, lf,mm,rt) \
    A0 = fmaf(wa, lf,   fmaf(wb, mm.x, fmaf(wc, mm.y, A0))); \
    A1 = fmaf(wa, mm.x, fmaf(wb, mm.y, fmaf(wc, mm.z, A1))); \
    A2 = fmaf(wa, mm.y, fmaf(wb, mm.z, fmaf(wc, mm.w, A2))); \
    A3 = fmaf(wa, mm.z, fmaf(wb, mm.w, fmaf(wc, rt,   A3)));

__global__ __launch_bounds__(192) void conv3_kernel(
        const float* __restrict__ y1p, const float* __restrict__ w,
        const float* __restrict__ g, const float* __restrict__ bta,
        const float* __restrict__ m, const float* __restrict__ vv,
        float* __restrict__ wk2) {
    int blk = blockIdx.x;
    int eg  = blk % (NENC / EG);       // 0..49, fastest -> consecutive blocks share y1p band
    int tmp = blk / (NENC / EG);       // b*3 + band
    int rb  = tmp % 3, b = tmp / 3;
    int e0  = eg * EG;
    int t   = threadIdx.x;
    int row = rb * 16 + t / 12;        // 0..47
    int c0  = (t % 12) * 4;            // 0,4,...,44
    const float* wb0 = w + (size_t)e0 * CMID * 9;
    const float* wb1 = wb0 + CMID * 9;
    const float* yb = y1p + (size_t)b * CMID * PLANE + row * PS + (c0 + PCOL0);

    float a00 = 0.f, a01 = 0.f, a02 = 0.f, a03 = 0.f;   // acc for e0
    float a10 = 0.f, a11 = 0.f, a12 = 0.f, a13 = 0.f;   // acc for e0+1

    // --- prologue: cm=0 data + weights ---
    float  lf0 = yb[-1];        float4 m0 = *(const float4*)yb;          float rt0 = yb[4];
    float  lf1 = yb[PS-1];      float4 m1 = *(const float4*)(yb+PS);     float rt1 = yb[PS+4];
    float  lf2 = yb[2*PS-1];    float4 m2 = *(const float4*)(yb+2*PS);   float rt2 = yb[2*PS+4];
    float u00 = wb0[0], u01 = wb0[1], u02 = wb0[2];
    float u10 = wb0[3], u11 = wb0[4], u12 = wb0[5];
    float u20 = wb0[6], u21 = wb0[7], u22 = wb0[8];
    float v00 = wb1[0], v01 = wb1[1], v02 = wb1[2];
    float v10 = wb1[3], v11 = wb1[4], v12 = wb1[5];
    float v20 = wb1[6], v21 = wb1[7], v22 = wb1[8];

    for (int cm = 0; cm < CMID - 1; ++cm) {
        // --- issue next iteration's loads (in flight under 72 FMAs) ---
        const float* yn = yb + (size_t)(cm + 1) * PLANE;
        float  nlf0 = yn[-1];       float4 nm0 = *(const float4*)yn;         float nrt0 = yn[4];
        float  nlf1 = yn[PS-1];     float4 nm1 = *(const float4*)(yn+PS);    float nrt1 = yn[PS+4];
        float  nlf2 = yn[2*PS-1];   float4 nm2 = *(const float4*)(yn+2*PS);  float nrt2 = yn[2*PS+4];
        const float* wn0 = wb0 + (cm + 1) * 9;
        const float* wn1 = wb1 + (cm + 1) * 9;
        float nu00 = wn0[0], nu01 = wn0[1], nu02 = wn0[2];
        float nu10 = wn0[3], nu11 = wn0[4], nu12 = wn0[5];
        float nu20 = wn0[6], nu21 = wn0[7], nu22 = wn0[8];
        float nv00 = wn1[0], nv01 = wn1[1], nv02 = wn1[2];
        float nv10 = wn1[3], nv11 = wn1[4], nv12 = wn1[5];
        float nv20 = wn1[6], nv21 = wn1[7], nv22 = wn1[8];

        FMA4(a00,a01,a02,a03, u00,u01,u02, lf0,m0,rt0)
        FMA4(a00,a01,a02,a03, u10,u11,u12, lf1,m1,rt1)
        FMA4(a00,a01,a02,a03, u20,u21,u22, lf2,m2,rt2)
        FMA4(a10,a11,a12,a13, v00,v01,v02, lf0,m0,rt0)
        FMA4(a10,a11,a12,a13, v10,v11,v12, lf1,m1,rt1)
        FMA4(a10,a11,a12,a13, v20,v21,v22, lf2,m2,rt2)

        lf0 = nlf0; m0 = nm0; rt0 = nrt0;
        lf1 = nlf1; m1 = nm1; rt1 = nrt1;
        lf2 = nlf2; m2 = nm2; rt2 = nrt2;
        u00 = nu00; u01 = nu01; u02 = nu02;
        u10 = nu10; u11 = nu11; u12 = nu12;
        u20 = nu20; u21 = nu21; u22 = nu22;
        v00 = nv00; v01 = nv01; v02 = nv02;
        v10 = nv10; v11 = nv11; v12 = nv12;
        v20 = nv20; v21 = nv21; v22 = nv22;
    }
    // --- peeled final iteration ---
    FMA4(a00,a01,a02,a03, u00,u01,u02, lf0,m0,rt0)
    FMA4(a00,a01,a02,a03, u10,u11,u12, lf1,m1,rt1)
    FMA4(a00,a01,a02,a03, u20,u21,u22, lf2,m2,rt2)
    FMA4(a10,a11,a12,a13, v00,v01,v02, lf0,m0,rt0)
    FMA4(a10,a11,a12,a13, v10,v11,v12, lf1,m1,rt1)
    FMA4(a10,a11,a12,a13, v20,v21,v22, lf2,m2,rt2)

    float sc0 = g[e0] * rsqrtf(vv[e0] + 1e-3f);
    float sh0 = bta[e0] - m[e0] * sc0;
    float sc1 = g[e0+1] * rsqrtf(vv[e0+1] + 1e-3f);
    float sh1 = bta[e0+1] - m[e0+1] * sc1;
    float* op = wk2 + (size_t)(b * NENC + e0) * HW + row * WW + c0;
    float4 o0 = {a00*sc0+sh0, a01*sc0+sh0, a02*sc0+sh0, a03*sc0+sh0};
    float4 o1 = {a10*sc1+sh1, a11*sc1+sh1, a12*sc1+sh1, a13*sc1+sh1};
    *(float4*)op = o0;
    *(float4*)(op + HW) = o1;
}

// ---------------- Kernel 5: pixel-shuffled softmax -> wsm[b][25][H2][W2] ----------------
__global__ void softmax_kernel(const float* __restrict__ wk2, float* __restrict__ wsm) {
    int idx = blockIdx.x * blockDim.x + threadIdx.x;
    const int total = BB * H2 * W2;
    if (idx >= total) return;
    int Wp = idx % W2, Hp = (idx / W2) % H2, b = idx / (H2 * W2);
    int h = Hp >> 1, w = Wp >> 1;
    int off = 2 * (Hp & 1) + (Wp & 1);
    const float* base = wk2 + (size_t)b * NENC * HW + (size_t)off * HW + h * WW + w;
    float vals[25];
    float mx = -1e30f;
#pragma unroll
    for (int k = 0; k < 25; k++) {
        float tv = base[(size_t)(4 * k) * HW];
        vals[k] = tv; mx = fmaxf(mx, tv);
    }
    float sum = 0.f;
#pragma unroll
    for (int k = 0; k < 25; k++) { float e2 = __expf(vals[k] - mx); vals[k] = e2; sum += e2; }
    float inv = 1.f / sum;
#pragma unroll
    for (int k = 0; k < 25; k++)
        wsm[((size_t)(b * 25 + k) * H2 + Hp) * W2 + Wp] = vals[k] * inv;
}

// ---------------- Kernel 6: CARAFE gather ----------------
__global__ void gather_kernel(const float* __restrict__ xg, const float* __restrict__ wsm,
                              float* __restrict__ out) {
    int idx = blockIdx.x * blockDim.x + threadIdx.x;
    const int total = BB * CB * HW;
    if (idx >= total) return;
    int w = idx % WW;
    int h = (idx / WW) % HH;
    int c = (idx / HW) % CB;
    int b = idx / (CB * HW);
    const float* xb = xg + ((size_t)b * CB + c) * HW;
    float xv[25];
#pragma unroll
    for (int i = 0; i < 5; i++) {
        int hy = h + i - 2;
        bool hok = (hy >= 0) && (hy < HH);
#pragma unroll
        for (int j = 0; j < 5; j++) {
            int wx = w + j - 2;
            bool ok = hok && (wx >= 0) && (wx < WW);
            xv[i * 5 + j] = ok ? xb[hy * WW + wx] : 0.f;
        }
    }
    float a0 = 0.f, a1 = 0.f, a2 = 0.f, a3 = 0.f;
    const float* wb = wsm + (size_t)b * 25 * H2 * W2;
    int r0 = (2 * h) * W2 + 2 * w;
#pragma unroll
    for (int k = 0; k < 25; k++) {
        const float* wkp = wb + (size_t)k * H2 * W2;
        float2 w0 = *(const float2*)(wkp + r0);
        float2 w1 = *(const float2*)(wkp + r0 + W2);
        float xk = xv[k];
        a0 = fmaf(w0.x, xk, a0);
        a1 = fmaf(w0.y, xk, a1);
        a2 = fmaf(w1.x, xk, a2);
        a3 = fmaf(w1.y, xk, a3);
    }
    float* ob = out + (((size_t)b * CB + c) * H2 + 2 * h) * W2 + 2 * w;
    float2 s0 = {a0, a1};
    float2 s1 = {a2, a3};
    *(float2*)ob = s0;
    *(float2*)(ob + W2) = s1;
}

extern "C" void kernel_launch(void* const* d_in, const int* in_sizes, int n_in,
                              void* d_out, int out_size, void* d_ws, size_t ws_size,
                              hipStream_t stream) {
    const float* x       = (const float*)d_in[0];
    const float* comp_w  = (const float*)d_in[1];
    const float* comp_g  = (const float*)d_in[2];
    const float* comp_b  = (const float*)d_in[3];
    const float* comp_m  = (const float*)d_in[4];
    const float* comp_v  = (const float*)d_in[5];
    const float* enc_w   = (const float*)d_in[6];
    const float* enc_g   = (const float*)d_in[7];
    const float* enc_b   = (const float*)d_in[8];
    const float* enc_m   = (const float*)d_in[9];
    const float* enc_v   = (const float*)d_in[10];
    float* out = (float*)d_out;

    float* ws = (float*)d_ws;
    float* gamma = ws;                                   // 64 (padded)
    float* xg    = ws + 64;                              // 1,179,648
    float* wk2   = xg + (size_t)BB * CB * HW;            // 921,600
    float* y1p   = wk2 + (size_t)BB * NENC * HW;         // 716,800 (dead after conv3)
    float* wsm   = y1p;                                  // 921,600 (overlays y1p region)
    // region after wk2 sized max(716,800, 921,600) = 921,600 floats
    // total floats: 64 + 1,179,648 + 921,600 + 921,600 = 3,022,912 (~12.1 MB)

    halo_kernel<<<(BB * CMID * 124) / 256, 256, 0, stream>>>(y1p);
    gamma_kernel<<<BB, 256, 0, stream>>>(x, gamma);
    {
        int total4 = BB * CB * HW / 4;
        pow_kernel<<<(total4 + 255) / 256, 256, 0, stream>>>(x, gamma, xg);
    }
    {
        int total = BB * CMID * (HW / 4);
        conv1_kernel<<<(total + 255) / 256, 256, 0, stream>>>(
            xg, comp_w, comp_g, comp_b, comp_m, comp_v, y1p);
    }
    conv3_kernel<<<BB * 3 * (NENC / EG), 192, 0, stream>>>(
        y1p, enc_w, enc_g, enc_b, enc_m, enc_v, wk2);
    {
        int total = BB * H2 * W2;
        softmax_kernel<<<(total + 255) / 256, 256, 0, stream>>>(wk2, wsm);
    }
    {
        int total = BB * CB * HW;
        gather_kernel<<<(total + 255) / 256, 256, 0, stream>>>(xg, wsm, out);
    }
}

// Round 11
// 168.080 us; speedup vs baseline: 1.7141x; 1.0270x over previous
//
#include <hip/hip_runtime.h>
#include <hip/hip_bf16.h>
#include <math.h>

#define CB   128   // input channels
#define CMID 64    // compressed channels
#define NENC 100   // encoder out channels (25 * 2 * 2)
#define HH   48
#define WW   48
#define BB   4
#define HW   (HH*WW)          // 2304
#define H2   (HH*2)           // 96
#define W2   (WW*2)           // 96
#define PS   56                // padded row stride: 224B -> rows 16B-aligned
#define PROWS 50               // 48 interior rows + 1 halo row each side
#define PCOL0 4                // interior starts at col 4
#define PLANE (PROWS*PS)       // 2800 floats per (b,cm) plane
#define EG   2                 // e-outputs per conv3 block (data reuse)

// ---------------- Kernel 0: zero ONLY the halo cells conv3 reads ----------------
__global__ void halo_kernel(float* __restrict__ y1p) {
    int idx = blockIdx.x * blockDim.x + threadIdx.x;   // plane*124 + t
    int plane = idx / 124;
    int t = idx % 124;
    float* p = y1p + (size_t)plane * PLANE;
    float4 z = make_float4(0.f, 0.f, 0.f, 0.f);
    if (t < 14) {
        *(float4*)(p + t * 4) = z;                     // row 0
    } else if (t < 28) {
        *(float4*)(p + 49 * PS + (t - 14) * 4) = z;    // row 49
    } else {
        int s = t - 28;                                 // 0..95
        int r = 1 + (s >> 1);                           // 1..48
        int col = (s & 1) ? 52 : 0;
        *(float4*)(p + r * PS + col) = z;
    }
}

// ---------------- Kernel 1: per-batch gamma (float4 loads) ----------------
__global__ void gamma_kernel(const float* __restrict__ x, float* __restrict__ gamma) {
    int b = blockIdx.x;
    const float* xb = x + (size_t)b * CB * HW;
    const float4* R4 = (const float4*)xb;
    const float4* G4 = (const float4*)(xb + HW);
    const float4* B4 = (const float4*)(xb + 2 * HW);
    float s = 0.f, s2 = 0.f;
    for (int i = threadIdx.x; i < HW / 4; i += blockDim.x) {
        float4 r = R4[i], g = G4[i], bl = B4[i];
        float g0 = 0.299f * r.x + 0.587f * g.x + 0.114f * bl.x;
        float g1 = 0.299f * r.y + 0.587f * g.y + 0.114f * bl.y;
        float g2 = 0.299f * r.z + 0.587f * g.z + 0.114f * bl.z;
        float g3 = 0.299f * r.w + 0.587f * g.w + 0.114f * bl.w;
        s  += (g0 + g1) + (g2 + g3);
        s2 += (g0 * g0 + g1 * g1) + (g2 * g2 + g3 * g3);
    }
    for (int o = 32; o > 0; o >>= 1) {
        s  += __shfl_down(s, o);
        s2 += __shfl_down(s2, o);
    }
    __shared__ float ss[4], ss2[4];
    int wid = threadIdx.x >> 6;
    if ((threadIdx.x & 63) == 0) { ss[wid] = s; ss2[wid] = s2; }
    __syncthreads();
    if (threadIdx.x == 0) {
        float S = 0.f, S2 = 0.f;
        int nw = blockDim.x >> 6;
        for (int i = 0; i < nw; i++) { S += ss[i]; S2 += ss2[i]; }
        const float N = (float)HW;
        float gm = S / N;
        float var = (S2 - S * S / N) / (N - 1.0f);
        var = fmaxf(var, 0.f);
        float gs = sqrtf(var);
        float gam = 0.8f + 0.4f * gm / (gm + fmaxf(gs, 1e-6f));
        gam = fminf(fmaxf(gam, 0.8f), 1.2f);
        gamma[b] = gam;
    }
}

// ---------------- Kernel 2: xg = pow(x + eps, gamma[b]) via fast log/exp ----------
__global__ void pow_kernel(const float* __restrict__ x, const float* __restrict__ gamma,
                           float* __restrict__ xg) {
    int idx = blockIdx.x * blockDim.x + threadIdx.x;
    const int total4 = BB * CB * HW / 4;
    if (idx >= total4) return;
    int b = idx / (CB * HW / 4);
    float gam = gamma[b];
    float4 xv = ((const float4*)x)[idx];
    float4 r;
    r.x = __expf(gam * __logf(xv.x + 1e-6f));
    r.y = __expf(gam * __logf(xv.y + 1e-6f));
    r.z = __expf(gam * __logf(xv.z + 1e-6f));
    r.w = __expf(gam * __logf(xv.w + 1e-6f));
    ((float4*)xg)[idx] = r;
}

// ---------------- Kernel 3: conv1x1 + BN + SiLU -> PADDED y1p ----------------
__global__ void conv1_kernel(const float* __restrict__ xg, const float* __restrict__ w,
                             const float* __restrict__ g, const float* __restrict__ bta,
                             const float* __restrict__ m, const float* __restrict__ vv,
                             float* __restrict__ y1p) {
    int idx = blockIdx.x * blockDim.x + threadIdx.x;
    const int PG = HW / 4;                 // 576 pixel-groups
    const int total = BB * CMID * PG;
    if (idx >= total) return;
    int pg = idx % PG;
    int cm = (idx / PG) % CMID;
    int b  = idx / (CMID * PG);
    const float4* xb = (const float4*)(xg + (size_t)b * CB * HW) + pg;
    const float* wc = w + cm * CB;
    float4 acc = {0.f, 0.f, 0.f, 0.f};
#pragma unroll 8
    for (int c = 0; c < CB; c++) {
        float4 xv = xb[(size_t)c * PG];
        float wv = wc[c];
        acc.x = fmaf(wv, xv.x, acc.x);
        acc.y = fmaf(wv, xv.y, acc.y);
        acc.z = fmaf(wv, xv.z, acc.z);
        acc.w = fmaf(wv, xv.w, acc.w);
    }
    float sc = g[cm] * rsqrtf(vv[cm] + 1e-3f);
    float sh = bta[cm] - m[cm] * sc;
    float4 o;
    float t;
    t = acc.x * sc + sh; o.x = t / (1.f + __expf(-t));
    t = acc.y * sc + sh; o.y = t / (1.f + __expf(-t));
    t = acc.z * sc + sh; o.z = t / (1.f + __expf(-t));
    t = acc.w * sc + sh; o.w = t / (1.f + __expf(-t));
    int row = pg / 12, col = (pg % 12) * 4;
    float* dst = y1p + ((size_t)(b * CMID + cm)) * PLANE + (row + 1) * PS + (col + PCOL0);
    *(float4*)dst = o;   // 16B-aligned
}

// ---------------- Kernel 4: conv3x3 + BN — e-blocked (EG=2) + dist-1 pipeline ----
// Output layout CHANGED to wk2n[b][25][HW][4] (4 sub-pixel channels contiguous)
#define FMA4(A0,A1,A2,A3, wa,wb,wc, lf,mm,rt) \
    A0 = fmaf(wa, lf,   fmaf(wb, mm.x, fmaf(wc, mm.y, A0))); \
    A1 = fmaf(wa, mm.x, fmaf(wb, mm.y, fmaf(wc, mm.z, A1))); \
    A2 = fmaf(wa, mm.y, fmaf(wb, mm.z, fmaf(wc, mm.w, A2))); \
    A3 = fmaf(wa, mm.z, fmaf(wb, mm.w, fmaf(wc, rt,   A3)));

__global__ __launch_bounds__(192) void conv3_kernel(
        const float* __restrict__ y1p, const float* __restrict__ w,
        const float* __restrict__ g, const float* __restrict__ bta,
        const float* __restrict__ m, const float* __restrict__ vv,
        float* __restrict__ wk2n) {
    int blk = blockIdx.x;
    int eg  = blk % (NENC / EG);       // fastest -> consecutive blocks share y1p band
    int tmp = blk / (NENC / EG);       // b*3 + band
    int rb  = tmp % 3, b = tmp / 3;
    int e0  = eg * EG;
    int t   = threadIdx.x;
    int row = rb * 16 + t / 12;        // 0..47
    int c0  = (t % 12) * 4;            // 0,4,...,44
    const float* wb0 = w + (size_t)e0 * CMID * 9;
    const float* wb1 = wb0 + CMID * 9;
    const float* yb = y1p + (size_t)b * CMID * PLANE + row * PS + (c0 + PCOL0);

    float a00 = 0.f, a01 = 0.f, a02 = 0.f, a03 = 0.f;   // acc for e0
    float a10 = 0.f, a11 = 0.f, a12 = 0.f, a13 = 0.f;   // acc for e0+1

    float  lf0 = yb[-1];        float4 m0 = *(const float4*)yb;          float rt0 = yb[4];
    float  lf1 = yb[PS-1];      float4 m1 = *(const float4*)(yb+PS);     float rt1 = yb[PS+4];
    float  lf2 = yb[2*PS-1];    float4 m2 = *(const float4*)(yb+2*PS);   float rt2 = yb[2*PS+4];
    float u00 = wb0[0], u01 = wb0[1], u02 = wb0[2];
    float u10 = wb0[3], u11 = wb0[4], u12 = wb0[5];
    float u20 = wb0[6], u21 = wb0[7], u22 = wb0[8];
    float v00 = wb1[0], v01 = wb1[1], v02 = wb1[2];
    float v10 = wb1[3], v11 = wb1[4], v12 = wb1[5];
    float v20 = wb1[6], v21 = wb1[7], v22 = wb1[8];

    for (int cm = 0; cm < CMID - 1; ++cm) {
        const float* yn = yb + (size_t)(cm + 1) * PLANE;
        float  nlf0 = yn[-1];       float4 nm0 = *(const float4*)yn;         float nrt0 = yn[4];
        float  nlf1 = yn[PS-1];     float4 nm1 = *(const float4*)(yn+PS);    float nrt1 = yn[PS+4];
        float  nlf2 = yn[2*PS-1];   float4 nm2 = *(const float4*)(yn+2*PS);  float nrt2 = yn[2*PS+4];
        const float* wn0 = wb0 + (cm + 1) * 9;
        const float* wn1 = wb1 + (cm + 1) * 9;
        float nu00 = wn0[0], nu01 = wn0[1], nu02 = wn0[2];
        float nu10 = wn0[3], nu11 = wn0[4], nu12 = wn0[5];
        float nu20 = wn0[6], nu21 = wn0[7], nu22 = wn0[8];
        float nv00 = wn1[0], nv01 = wn1[1], nv02 = wn1[2];
        float nv10 = wn1[3], nv11 = wn1[4], nv12 = wn1[5];
        float nv20 = wn1[6], nv21 = wn1[7], nv22 = wn1[8];

        FMA4(a00,a01,a02,a03, u00,u01,u02, lf0,m0,rt0)
        FMA4(a00,a01,a02,a03, u10,u11,u12, lf1,m1,rt1)
        FMA4(a00,a01,a02,a03, u20,u21,u22, lf2,m2,rt2)
        FMA4(a10,a11,a12,a13, v00,v01,v02, lf0,m0,rt0)
        FMA4(a10,a11,a12,a13, v10,v11,v12, lf1,m1,rt1)
        FMA4(a10,a11,a12,a13, v20,v21,v22, lf2,m2,rt2)

        lf0 = nlf0; m0 = nm0; rt0 = nrt0;
        lf1 = nlf1; m1 = nm1; rt1 = nrt1;
        lf2 = nlf2; m2 = nm2; rt2 = nrt2;
        u00 = nu00; u01 = nu01; u02 = nu02;
        u10 = nu10; u11 = nu11; u12 = nu12;
        u20 = nu20; u21 = nu21; u22 = nu22;
        v00 = nv00; v01 = nv01; v02 = nv02;
        v10 = nv10; v11 = nv11; v12 = nv12;
        v20 = nv20; v21 = nv21; v22 = nv22;
    }
    FMA4(a00,a01,a02,a03, u00,u01,u02, lf0,m0,rt0)
    FMA4(a00,a01,a02,a03, u10,u11,u12, lf1,m1,rt1)
    FMA4(a00,a01,a02,a03, u20,u21,u22, lf2,m2,rt2)
    FMA4(a10,a11,a12,a13, v00,v01,v02, lf0,m0,rt0)
    FMA4(a10,a11,a12,a13, v10,v11,v12, lf1,m1,rt1)
    FMA4(a10,a11,a12,a13, v20,v21,v22, lf2,m2,rt2)

    float sc0 = g[e0] * rsqrtf(vv[e0] + 1e-3f);
    float sh0 = bta[e0] - m[e0] * sc0;
    float sc1 = g[e0+1] * rsqrtf(vv[e0+1] + 1e-3f);
    float sh1 = bta[e0+1] - m[e0+1] * sc1;
    // wk2n[b][25][HW][4]: e = 4k+off; e0 even -> (k, off0) and (k, off0+1)
    int kk = e0 >> 2, off0 = e0 & 3;
    float* op = wk2n + (((size_t)(b * 25 + kk) * HW + row * WW + c0) << 2) + off0;
    *(float2*)(op + 0)  = make_float2(a00*sc0+sh0, a10*sc1+sh1);
    *(float2*)(op + 4)  = make_float2(a01*sc0+sh0, a11*sc1+sh1);
    *(float2*)(op + 8)  = make_float2(a02*sc0+sh0, a12*sc1+sh1);
    *(float2*)(op + 12) = make_float2(a03*sc0+sh0, a13*sc1+sh1);
}

// ---------------- Kernel 5: fused softmax + CARAFE gather ----------------
// block = (b, h, whalf): stage scores -> LDS softmax (once) -> all 128 c reuse.
// phase2 thread = (c, q): 12 source cols in 3 register-rotated 4-wide steps.
__global__ __launch_bounds__(256) void sg_kernel(const float* __restrict__ xg,
                                                 const float* __restrict__ wk2n,
                                                 float* __restrict__ out) {
    int blk = blockIdx.x;                  // ((b*48 + h)<<1) | whalf
    int whalf = blk & 1;
    int bh = blk >> 1;
    int h = bh % HH, b = bh / HH;
    int tid = threadIdx.x;

    __shared__ float raw[25 * 24 * 4];     // [k][w_l][off]
    __shared__ float wsm[25 * 2 * 48];     // [k][si][Wp_l]

    // phase 1a: cooperative load of the (25 x 24 x 4) score slice
    {
        const float4* w4p = (const float4*)wk2n;
        size_t base4 = (size_t)b * 25 * HW + h * WW + whalf * 24;
        float4* raw4 = (float4*)raw;
        for (int t = tid; t < 600; t += 256) {
            int k = t / 24, wl = t % 24;
            raw4[t] = w4p[base4 + (size_t)k * HW + wl];
        }
    }
    __syncthreads();
    // phase 1b: 96 softmaxes (w_l x 4 sub-pixels)
    if (tid < 96) {
        int wl = tid >> 2, off = tid & 3;
        float v[25]; float mx = -1e30f;
#pragma unroll
        for (int k = 0; k < 25; k++) { v[k] = raw[(k * 24 + wl) * 4 + off]; mx = fmaxf(mx, v[k]); }
        float sum = 0.f;
#pragma unroll
        for (int k = 0; k < 25; k++) { v[k] = __expf(v[k] - mx); sum += v[k]; }
        float inv = 1.f / sum;
        int si = off >> 1, sj = off & 1;
#pragma unroll
        for (int k = 0; k < 25; k++) wsm[k * 96 + si * 48 + 2 * wl + sj] = v[k] * inv;
    }
    __syncthreads();

    // phase 2: gather
    int c = tid >> 1, q = tid & 1;
    const float* xb = xg + ((size_t)b * CB + c) * HW;
    int wbase = whalf * 24 + q * 12;       // global source-col start of this thread
    float* ob = out + (((size_t)b * CB + c) * H2 + 2 * h) * W2;
    const float4* wsm4 = (const float4*)wsm;
    const float4 Z4 = make_float4(0.f, 0.f, 0.f, 0.f);

    // window registers: cols [wc-4, wc+8) as 3 float4-cols x 5 rows
    float4 A[5], Bv[5], Cv[5];
#pragma unroll
    for (int i = 0; i < 5; i++) {
        int hr = h + i - 2;
        bool rv = (hr >= 0) && (hr < HH);
        const float* rp = xb + hr * WW;
        A[i]  = (rv && wbase > 0) ? *(const float4*)(rp + wbase - 4) : Z4;
        Bv[i] = rv                ? *(const float4*)(rp + wbase)     : Z4;
        Cv[i] = rv                ? *(const float4*)(rp + wbase + 4) : Z4;   // wbase+4 <= 40 always
    }

#pragma unroll
    for (int s = 0; s < 3; s++) {
        int wc = wbase + 4 * s;
        float acc0[8], acc1[8];
#pragma unroll
        for (int p = 0; p < 8; p++) { acc0[p] = 0.f; acc1[p] = 0.f; }
#pragma unroll
        for (int i = 0; i < 5; i++) {
            float xv[12] = {A[i].x, A[i].y, A[i].z, A[i].w,
                            Bv[i].x, Bv[i].y, Bv[i].z, Bv[i].w,
                            Cv[i].x, Cv[i].y, Cv[i].z, Cv[i].w};
#pragma unroll
            for (int j = 0; j < 5; j++) {
                int k = i * 5 + j;
                float4 w0a = wsm4[k * 24 + 6 * q + 2 * s];
                float4 w0b = wsm4[k * 24 + 6 * q + 2 * s + 1];
                float4 w1a = wsm4[k * 24 + 12 + 6 * q + 2 * s];
                float4 w1b = wsm4[k * 24 + 12 + 6 * q + 2 * s + 1];
                float x0 = xv[j + 2], x1 = xv[j + 3], x2 = xv[j + 4], x3 = xv[j + 5];
                acc0[0] = fmaf(w0a.x, x0, acc0[0]); acc0[1] = fmaf(w0a.y, x0, acc0[1]);
                acc0[2] = fmaf(w0a.z, x1, acc0[2]); acc0[3] = fmaf(w0a.w, x1, acc0[3]);
                acc0[4] = fmaf(w0b.x, x2, acc0[4]); acc0[5] = fmaf(w0b.y, x2, acc0[5]);
                acc0[6] = fmaf(w0b.z, x3, acc0[6]); acc0[7] = fmaf(w0b.w, x3, acc0[7]);
                acc1[0] = fmaf(w1a.x, x0, acc1[0]); acc1[1] = fmaf(w1a.y, x0, acc1[1]);
                acc1[2] = fmaf(w1a.z, x1, acc1[2]); acc1[3] = fmaf(w1a.w, x1, acc1[3]);
                acc1[4] = fmaf(w1b.x, x2, acc1[4]); acc1[5] = fmaf(w1b.y, x2, acc1[5]);
                acc1[6] = fmaf(w1b.z, x3, acc1[6]); acc1[7] = fmaf(w1b.w, x3, acc1[7]);
            }
        }
        int colg = whalf * 48 + 24 * q + 8 * s;
        *(float4*)(ob + colg)          = make_float4(acc0[0], acc0[1], acc0[2], acc0[3]);
        *(float4*)(ob + colg + 4)      = make_float4(acc0[4], acc0[5], acc0[6], acc0[7]);
        *(float4*)(ob + W2 + colg)     = make_float4(acc1[0], acc1[1], acc1[2], acc1[3]);
        *(float4*)(ob + W2 + colg + 4) = make_float4(acc1[4], acc1[5], acc1[6], acc1[7]);
        if (s < 2) {
            int nc = wc + 8;
#pragma unroll
            for (int i = 0; i < 5; i++) {
                int hr = h + i - 2;
                bool rv = (hr >= 0) && (hr < HH);
                A[i] = Bv[i]; Bv[i] = Cv[i];
                Cv[i] = (rv && nc < WW) ? *(const float4*)(xb + hr * WW + nc) : Z4;
            }
        }
    }
}

extern "C" void kernel_launch(void* const* d_in, const int* in_sizes, int n_in,
                              void* d_out, int out_size, void* d_ws, size_t ws_size,
                              hipStream_t stream) {
    const float* x       = (const float*)d_in[0];
    const float* comp_w  = (const float*)d_in[1];
    const float* comp_g  = (const float*)d_in[2];
    const float* comp_b  = (const float*)d_in[3];
    const float* comp_m  = (const float*)d_in[4];
    const float* comp_v  = (const float*)d_in[5];
    const float* enc_w   = (const float*)d_in[6];
    const float* enc_g   = (const float*)d_in[7];
    const float* enc_b   = (const float*)d_in[8];
    const float* enc_m   = (const float*)d_in[9];
    const float* enc_v   = (const float*)d_in[10];
    float* out = (float*)d_out;

    float* ws = (float*)d_ws;
    float* gamma = ws;                                   // 64 (padded)
    float* xg    = ws + 64;                              // 1,179,648
    float* wk2n  = xg + (size_t)BB * CB * HW;            // 921,600  [b][25][HW][4]
    float* y1p   = wk2n + (size_t)BB * 25 * HW * 4;      // 716,800
    // total floats: 64 + 1,179,648 + 921,600 + 716,800 = 2,818,112 (~11.3 MB)

    halo_kernel<<<(BB * CMID * 124) / 256, 256, 0, stream>>>(y1p);
    gamma_kernel<<<BB, 256, 0, stream>>>(x, gamma);
    {
        int total4 = BB * CB * HW / 4;
        pow_kernel<<<(total4 + 255) / 256, 256, 0, stream>>>(x, gamma, xg);
    }
    {
        int total = BB * CMID * (HW / 4);
        conv1_kernel<<<(total + 255) / 256, 256, 0, stream>>>(
            xg, comp_w, comp_g, comp_b, comp_m, comp_v, y1p);
    }
    conv3_kernel<<<BB * 3 * (NENC / EG), 192, 0, stream>>>(
        y1p, enc_w, enc_g, enc_b, enc_m, enc_v, wk2n);
    sg_kernel<<<BB * HH * 2, 256, 0, stream>>>(xg, wk2n, out);
}

// Round 12
// 163.289 us; speedup vs baseline: 1.7644x; 1.0293x over previous
//
#include <hip/hip_runtime.h>
#include <hip/hip_bf16.h>
#include <math.h>

#define CB   128   // input channels
#define CMID 64    // compressed channels
#define NENC 100   // encoder out channels (25 * 2 * 2)
#define HH   48
#define WW   48
#define BB   4
#define HW   (HH*WW)          // 2304
#define H2   (HH*2)           // 96
#define W2   (WW*2)           // 96
#define PS   56                // padded row stride: 224B -> rows 16B-aligned
#define PROWS 50               // 48 interior rows + 1 halo row each side
#define PCOL0 4                // interior starts at col 4
#define PLANE (PROWS*PS)       // 2800 floats per (b,cm) plane
#define EG   2                 // e-outputs per conv3 block (data reuse)
#define NHALO4 (BB*CMID*124)   // 31744 halo float4s

// ---------------- Kernel 1: fused gamma-reduce + pow + halo-zero ----------------
// grid = 1152 blocks x 256 thr; block bid handles f4 range [bid*256, bid*256+256)
// of x (batch b = bid/288). Each block redundantly reduces its batch's gray
// image (27KB, L2-broadcast) to compute gamma -> no separate kernel + sync.
// Threads with global idx < NHALO4 also zero one halo float4 of y1p.
__global__ __launch_bounds__(256) void pow_kernel(const float* __restrict__ x,
                                                  float* __restrict__ xg,
                                                  float* __restrict__ y1p) {
    int tid = threadIdx.x;
    int bid = blockIdx.x;
    int b = bid / (CB * HW / 4 / 256);        // 288 blocks per batch

    // --- per-block gamma reduction over gray(batch b) ---
    const float* xb = x + (size_t)b * CB * HW;
    const float4* R4 = (const float4*)xb;
    const float4* G4 = (const float4*)(xb + HW);
    const float4* B4 = (const float4*)(xb + 2 * HW);
    float s = 0.f, s2 = 0.f;
    for (int i = tid; i < HW / 4; i += 256) {
        float4 r = R4[i], g = G4[i], bl = B4[i];
        float g0 = 0.299f * r.x + 0.587f * g.x + 0.114f * bl.x;
        float g1 = 0.299f * r.y + 0.587f * g.y + 0.114f * bl.y;
        float g2 = 0.299f * r.z + 0.587f * g.z + 0.114f * bl.z;
        float g3 = 0.299f * r.w + 0.587f * g.w + 0.114f * bl.w;
        s  += (g0 + g1) + (g2 + g3);
        s2 += (g0 * g0 + g1 * g1) + (g2 * g2 + g3 * g3);
    }
    for (int o = 32; o > 0; o >>= 1) {
        s  += __shfl_down(s, o);
        s2 += __shfl_down(s2, o);
    }
    __shared__ float ss[4], ss2[4], gsh;
    int wid = tid >> 6;
    if ((tid & 63) == 0) { ss[wid] = s; ss2[wid] = s2; }
    __syncthreads();
    if (tid == 0) {
        float S = ss[0] + ss[1] + ss[2] + ss[3];
        float S2 = ss2[0] + ss2[1] + ss2[2] + ss2[3];
        const float N = (float)HW;
        float gm = S / N;
        float var = (S2 - S * S / N) / (N - 1.0f);
        var = fmaxf(var, 0.f);
        float gs = sqrtf(var);
        float gam = 0.8f + 0.4f * gm / (gm + fmaxf(gs, 1e-6f));
        gsh = fminf(fmaxf(gam, 0.8f), 1.2f);
    }
    __syncthreads();
    float gam = gsh;

    // --- pow transform (1 float4 per thread) ---
    int idx = bid * 256 + tid;
    float4 xv = ((const float4*)x)[idx];
    float4 r;
    r.x = __expf(gam * __logf(xv.x + 1e-6f));
    r.y = __expf(gam * __logf(xv.y + 1e-6f));
    r.z = __expf(gam * __logf(xv.z + 1e-6f));
    r.w = __expf(gam * __logf(xv.w + 1e-6f));
    ((float4*)xg)[idx] = r;

    // --- halo zeroing (threads 0..NHALO4-1) ---
    if (idx < NHALO4) {
        int plane = idx / 124;
        int t = idx % 124;
        float* p = y1p + (size_t)plane * PLANE;
        float4 z = make_float4(0.f, 0.f, 0.f, 0.f);
        if (t < 14) {
            *(float4*)(p + t * 4) = z;                     // row 0
        } else if (t < 28) {
            *(float4*)(p + 49 * PS + (t - 14) * 4) = z;    // row 49
        } else {
            int sIdx = t - 28;                              // 0..95
            int rr = 1 + (sIdx >> 1);                       // 1..48
            int col = (sIdx & 1) ? 52 : 0;
            *(float4*)(p + rr * PS + col) = z;
        }
    }
}

// ---------------- Kernel 2: conv1x1 + BN + SiLU -> PADDED y1p ----------------
__global__ void conv1_kernel(const float* __restrict__ xg, const float* __restrict__ w,
                             const float* __restrict__ g, const float* __restrict__ bta,
                             const float* __restrict__ m, const float* __restrict__ vv,
                             float* __restrict__ y1p) {
    int idx = blockIdx.x * blockDim.x + threadIdx.x;
    const int PG = HW / 4;                 // 576 pixel-groups
    const int total = BB * CMID * PG;
    if (idx >= total) return;
    int pg = idx % PG;
    int cm = (idx / PG) % CMID;
    int b  = idx / (CMID * PG);
    const float4* xb = (const float4*)(xg + (size_t)b * CB * HW) + pg;
    const float* wc = w + cm * CB;
    float4 acc = {0.f, 0.f, 0.f, 0.f};
#pragma unroll 8
    for (int c = 0; c < CB; c++) {
        float4 xv = xb[(size_t)c * PG];
        float wv = wc[c];
        acc.x = fmaf(wv, xv.x, acc.x);
        acc.y = fmaf(wv, xv.y, acc.y);
        acc.z = fmaf(wv, xv.z, acc.z);
        acc.w = fmaf(wv, xv.w, acc.w);
    }
    float sc = g[cm] * rsqrtf(vv[cm] + 1e-3f);
    float sh = bta[cm] - m[cm] * sc;
    float4 o;
    float t;
    t = acc.x * sc + sh; o.x = t / (1.f + __expf(-t));
    t = acc.y * sc + sh; o.y = t / (1.f + __expf(-t));
    t = acc.z * sc + sh; o.z = t / (1.f + __expf(-t));
    t = acc.w * sc + sh; o.w = t / (1.f + __expf(-t));
    int row = pg / 12, col = (pg % 12) * 4;
    float* dst = y1p + ((size_t)(b * CMID + cm)) * PLANE + (row + 1) * PS + (col + PCOL0);
    *(float4*)dst = o;   // 16B-aligned
}

// ---------------- Kernel 3: conv3x3 + BN — e-blocked (EG=2) + dist-1 pipeline ----
// Output layout wk2n[b][25][HW][4] (4 sub-pixel channels contiguous)
#define FMA4(A0,A1,A2,A3, wa,wb,wc, lf,mm,rt) \
    A0 = fmaf(wa, lf,   fmaf(wb, mm.x, fmaf(wc, mm.y, A0))); \
    A1 = fmaf(wa, mm.x, fmaf(wb, mm.y, fmaf(wc, mm.z, A1))); \
    A2 = fmaf(wa, mm.y, fmaf(wb, mm.z, fmaf(wc, mm.w, A2))); \
    A3 = fmaf(wa, mm.z, fmaf(wb, mm.w, fmaf(wc, rt,   A3)));

__global__ __launch_bounds__(192) void conv3_kernel(
        const float* __restrict__ y1p, const float* __restrict__ w,
        const float* __restrict__ g, const float* __restrict__ bta,
        const float* __restrict__ m, const float* __restrict__ vv,
        float* __restrict__ wk2n) {
    int blk = blockIdx.x;
    int eg  = blk % (NENC / EG);       // fastest -> consecutive blocks share y1p band
    int tmp = blk / (NENC / EG);       // b*3 + band
    int rb  = tmp % 3, b = tmp / 3;
    int e0  = eg * EG;
    int t   = threadIdx.x;
    int row = rb * 16 + t / 12;        // 0..47
    int c0  = (t % 12) * 4;            // 0,4,...,44
    const float* wb0 = w + (size_t)e0 * CMID * 9;
    const float* wb1 = wb0 + CMID * 9;
    const float* yb = y1p + (size_t)b * CMID * PLANE + row * PS + (c0 + PCOL0);

    float a00 = 0.f, a01 = 0.f, a02 = 0.f, a03 = 0.f;   // acc for e0
    float a10 = 0.f, a11 = 0.f, a12 = 0.f, a13 = 0.f;   // acc for e0+1

    float  lf0 = yb[-1];        float4 m0 = *(const float4*)yb;          float rt0 = yb[4];
    float  lf1 = yb[PS-1];      float4 m1 = *(const float4*)(yb+PS);     float rt1 = yb[PS+4];
    float  lf2 = yb[2*PS-1];    float4 m2 = *(const float4*)(yb+2*PS);   float rt2 = yb[2*PS+4];
    float u00 = wb0[0], u01 = wb0[1], u02 = wb0[2];
    float u10 = wb0[3], u11 = wb0[4], u12 = wb0[5];
    float u20 = wb0[6], u21 = wb0[7], u22 = wb0[8];
    float v00 = wb1[0], v01 = wb1[1], v02 = wb1[2];
    float v10 = wb1[3], v11 = wb1[4], v12 = wb1[5];
    float v20 = wb1[6], v21 = wb1[7], v22 = wb1[8];

    for (int cm = 0; cm < CMID - 1; ++cm) {
        const float* yn = yb + (size_t)(cm + 1) * PLANE;
        float  nlf0 = yn[-1];       float4 nm0 = *(const float4*)yn;         float nrt0 = yn[4];
        float  nlf1 = yn[PS-1];     float4 nm1 = *(const float4*)(yn+PS);    float nrt1 = yn[PS+4];
        float  nlf2 = yn[2*PS-1];   float4 nm2 = *(const float4*)(yn+2*PS);  float nrt2 = yn[2*PS+4];
        const float* wn0 = wb0 + (cm + 1) * 9;
        const float* wn1 = wb1 + (cm + 1) * 9;
        float nu00 = wn0[0], nu01 = wn0[1], nu02 = wn0[2];
        float nu10 = wn0[3], nu11 = wn0[4], nu12 = wn0[5];
        float nu20 = wn0[6], nu21 = wn0[7], nu22 = wn0[8];
        float nv00 = wn1[0], nv01 = wn1[1], nv02 = wn1[2];
        float nv10 = wn1[3], nv11 = wn1[4], nv12 = wn1[5];
        float nv20 = wn1[6], nv21 = wn1[7], nv22 = wn1[8];

        FMA4(a00,a01,a02,a03, u00,u01,u02, lf0,m0,rt0)
        FMA4(a00,a01,a02,a03, u10,u11,u12, lf1,m1,rt1)
        FMA4(a00,a01,a02,a03, u20,u21,u22, lf2,m2,rt2)
        FMA4(a10,a11,a12,a13, v00,v01,v02, lf0,m0,rt0)
        FMA4(a10,a11,a12,a13, v10,v11,v12, lf1,m1,rt1)
        FMA4(a10,a11,a12,a13, v20,v21,v22, lf2,m2,rt2)

        lf0 = nlf0; m0 = nm0; rt0 = nrt0;
        lf1 = nlf1; m1 = nm1; rt1 = nrt1;
        lf2 = nlf2; m2 = nm2; rt2 = nrt2;
        u00 = nu00; u01 = nu01; u02 = nu02;
        u10 = nu10; u11 = nu11; u12 = nu12;
        u20 = nu20; u21 = nu21; u22 = nu22;
        v00 = nv00; v01 = nv01; v02 = nv02;
        v10 = nv10; v11 = nv11; v12 = nv12;
        v20 = nv20; v21 = nv21; v22 = nv22;
    }
    FMA4(a00,a01,a02,a03, u00,u01,u02, lf0,m0,rt0)
    FMA4(a00,a01,a02,a03, u10,u11,u12, lf1,m1,rt1)
    FMA4(a00,a01,a02,a03, u20,u21,u22, lf2,m2,rt2)
    FMA4(a10,a11,a12,a13, v00,v01,v02, lf0,m0,rt0)
    FMA4(a10,a11,a12,a13, v10,v11,v12, lf1,m1,rt1)
    FMA4(a10,a11,a12,a13, v20,v21,v22, lf2,m2,rt2)

    float sc0 = g[e0] * rsqrtf(vv[e0] + 1e-3f);
    float sh0 = bta[e0] - m[e0] * sc0;
    float sc1 = g[e0+1] * rsqrtf(vv[e0+1] + 1e-3f);
    float sh1 = bta[e0+1] - m[e0+1] * sc1;
    int kk = e0 >> 2, off0 = e0 & 3;
    float* op = wk2n + (((size_t)(b * 25 + kk) * HW + row * WW + c0) << 2) + off0;
    *(float2*)(op + 0)  = make_float2(a00*sc0+sh0, a10*sc1+sh1);
    *(float2*)(op + 4)  = make_float2(a01*sc0+sh0, a11*sc1+sh1);
    *(float2*)(op + 8)  = make_float2(a02*sc0+sh0, a12*sc1+sh1);
    *(float2*)(op + 12) = make_float2(a03*sc0+sh0, a13*sc1+sh1);
}

// ---------------- Kernel 4: fused softmax + CARAFE gather ----------------
__global__ __launch_bounds__(256) void sg_kernel(const float* __restrict__ xg,
                                                 const float* __restrict__ wk2n,
                                                 float* __restrict__ out) {
    int blk = blockIdx.x;                  // ((b*48 + h)<<1) | whalf
    int whalf = blk & 1;
    int bh = blk >> 1;
    int h = bh % HH, b = bh / HH;
    int tid = threadIdx.x;

    __shared__ float raw[25 * 24 * 4];     // [k][w_l][off]
    __shared__ float wsm[25 * 2 * 48];     // [k][si][Wp_l]

    {
        const float4* w4p = (const float4*)wk2n;
        size_t base4 = (size_t)b * 25 * HW + h * WW + whalf * 24;
        float4* raw4 = (float4*)raw;
        for (int t = tid; t < 600; t += 256) {
            int k = t / 24, wl = t % 24;
            raw4[t] = w4p[base4 + (size_t)k * HW + wl];
        }
    }
    __syncthreads();
    if (tid < 96) {
        int wl = tid >> 2, off = tid & 3;
        float v[25]; float mx = -1e30f;
#pragma unroll
        for (int k = 0; k < 25; k++) { v[k] = raw[(k * 24 + wl) * 4 + off]; mx = fmaxf(mx, v[k]); }
        float sum = 0.f;
#pragma unroll
        for (int k = 0; k < 25; k++) { v[k] = __expf(v[k] - mx); sum += v[k]; }
        float inv = 1.f / sum;
        int si = off >> 1, sj = off & 1;
#pragma unroll
        for (int k = 0; k < 25; k++) wsm[k * 96 + si * 48 + 2 * wl + sj] = v[k] * inv;
    }
    __syncthreads();

    int c = tid >> 1, q = tid & 1;
    const float* xb = xg + ((size_t)b * CB + c) * HW;
    int wbase = whalf * 24 + q * 12;
    float* ob = out + (((size_t)b * CB + c) * H2 + 2 * h) * W2;
    const float4* wsm4 = (const float4*)wsm;
    const float4 Z4 = make_float4(0.f, 0.f, 0.f, 0.f);

    float4 A[5], Bv[5], Cv[5];
#pragma unroll
    for (int i = 0; i < 5; i++) {
        int hr = h + i - 2;
        bool rv = (hr >= 0) && (hr < HH);
        const float* rp = xb + hr * WW;
        A[i]  = (rv && wbase > 0) ? *(const float4*)(rp + wbase - 4) : Z4;
        Bv[i] = rv                ? *(const float4*)(rp + wbase)     : Z4;
        Cv[i] = rv                ? *(const float4*)(rp + wbase + 4) : Z4;
    }

#pragma unroll
    for (int s = 0; s < 3; s++) {
        int wc = wbase + 4 * s;
        float acc0[8], acc1[8];
#pragma unroll
        for (int p = 0; p < 8; p++) { acc0[p] = 0.f; acc1[p] = 0.f; }
#pragma unroll
        for (int i = 0; i < 5; i++) {
            float xv[12] = {A[i].x, A[i].y, A[i].z, A[i].w,
                            Bv[i].x, Bv[i].y, Bv[i].z, Bv[i].w,
                            Cv[i].x, Cv[i].y, Cv[i].z, Cv[i].w};
#pragma unroll
            for (int j = 0; j < 5; j++) {
                int k = i * 5 + j;
                float4 w0a = wsm4[k * 24 + 6 * q + 2 * s];
                float4 w0b = wsm4[k * 24 + 6 * q + 2 * s + 1];
                float4 w1a = wsm4[k * 24 + 12 + 6 * q + 2 * s];
                float4 w1b = wsm4[k * 24 + 12 + 6 * q + 2 * s + 1];
                float x0 = xv[j + 2], x1 = xv[j + 3], x2 = xv[j + 4], x3 = xv[j + 5];
                acc0[0] = fmaf(w0a.x, x0, acc0[0]); acc0[1] = fmaf(w0a.y, x0, acc0[1]);
                acc0[2] = fmaf(w0a.z, x1, acc0[2]); acc0[3] = fmaf(w0a.w, x1, acc0[3]);
                acc0[4] = fmaf(w0b.x, x2, acc0[4]); acc0[5] = fmaf(w0b.y, x2, acc0[5]);
                acc0[6] = fmaf(w0b.z, x3, acc0[6]); acc0[7] = fmaf(w0b.w, x3, acc0[7]);
                acc1[0] = fmaf(w1a.x, x0, acc1[0]); acc1[1] = fmaf(w1a.y, x0, acc1[1]);
                acc1[2] = fmaf(w1a.z, x1, acc1[2]); acc1[3] = fmaf(w1a.w, x1, acc1[3]);
                acc1[4] = fmaf(w1b.x, x2, acc1[4]); acc1[5] = fmaf(w1b.y, x2, acc1[5]);
                acc1[6] = fmaf(w1b.z, x3, acc1[6]); acc1[7] = fmaf(w1b.w, x3, acc1[7]);
            }
        }
        int colg = whalf * 48 + 24 * q + 8 * s;
        *(float4*)(ob + colg)          = make_float4(acc0[0], acc0[1], acc0[2], acc0[3]);
        *(float4*)(ob + colg + 4)      = make_float4(acc0[4], acc0[5], acc0[6], acc0[7]);
        *(float4*)(ob + W2 + colg)     = make_float4(acc1[0], acc1[1], acc1[2], acc1[3]);
        *(float4*)(ob + W2 + colg + 4) = make_float4(acc1[4], acc1[5], acc1[6], acc1[7]);
        if (s < 2) {
            int nc = wc + 8;
#pragma unroll
            for (int i = 0; i < 5; i++) {
                int hr = h + i - 2;
                bool rv = (hr >= 0) && (hr < HH);
                A[i] = Bv[i]; Bv[i] = Cv[i];
                Cv[i] = (rv && nc < WW) ? *(const float4*)(xb + hr * WW + nc) : Z4;
            }
        }
    }
}

extern "C" void kernel_launch(void* const* d_in, const int* in_sizes, int n_in,
                              void* d_out, int out_size, void* d_ws, size_t ws_size,
                              hipStream_t stream) {
    const float* x       = (const float*)d_in[0];
    const float* comp_w  = (const float*)d_in[1];
    const float* comp_g  = (const float*)d_in[2];
    const float* comp_b  = (const float*)d_in[3];
    const float* comp_m  = (const float*)d_in[4];
    const float* comp_v  = (const float*)d_in[5];
    const float* enc_w   = (const float*)d_in[6];
    const float* enc_g   = (const float*)d_in[7];
    const float* enc_b   = (const float*)d_in[8];
    const float* enc_m   = (const float*)d_in[9];
    const float* enc_v   = (const float*)d_in[10];
    float* out = (float*)d_out;

    float* ws = (float*)d_ws;
    float* xg    = ws;                                   // 1,179,648
    float* wk2n  = xg + (size_t)BB * CB * HW;            // 921,600  [b][25][HW][4]
    float* y1p   = wk2n + (size_t)BB * 25 * HW * 4;      // 716,800
    // total floats: 1,179,648 + 921,600 + 716,800 = 2,818,048 (~11.3 MB)

    {   // fused gamma + pow + halo-zero
        int total4 = BB * CB * HW / 4;                   // 294,912 -> 1152 blocks
        pow_kernel<<<total4 / 256, 256, 0, stream>>>(x, xg, y1p);
    }
    {
        int total = BB * CMID * (HW / 4);
        conv1_kernel<<<(total + 255) / 256, 256, 0, stream>>>(
            xg, comp_w, comp_g, comp_b, comp_m, comp_v, y1p);
    }
    conv3_kernel<<<BB * 3 * (NENC / EG), 192, 0, stream>>>(
        y1p, enc_w, enc_g, enc_b, enc_m, enc_v, wk2n);
    sg_kernel<<<BB * HH * 2, 256, 0, stream>>>(xg, wk2n, out);
}